// Round 3
// baseline (4895.594 us; speedup 1.0000x reference)
//
#include <hip/hip_runtime.h>
#include <math.h>

// ---------------- constants ----------------
#define DTMEM 0.1f   // DT*TAU_MEM_INV
#define DTSYN 0.2f   // DT*TAU_SYN_INV
#define DTTR  0.02f  // DT*TAU_PRE_INV == DT*TAU_POST_INV

static constexpr int B = 32, T = 32;
static constexpr int HD = 60, H1 = 56, HP = 28, H2 = 24;
static constexpr int LD  = HD*HD;   // 3600
static constexpr int LP  = HP*HP;   // 784

// lif0 state: thread-slot-major [b][og:8][yh:2][i:7][tid:448] float2 (v0/i0 now live in REGISTERS)
static constexpr size_t SST  = (size_t)B*8*2*7*448*2;          // floats
// conv2 state: thread-slot-major [b][jg:13][slot:6][tid:192] float4
static constexpr size_t SST2 = (size_t)B*13*6*192*4;           // floats

static constexpr size_t OW1   = 0;                             // w1 buffer A (1500)
static constexpr size_t OV0   = OW1 + 1500;                    // (unused now - registers)
static constexpr size_t OI0   = OV0   + SST;                   // (unused now - registers)
static constexpr size_t OTQ1  = OI0   + SST;
static constexpr size_t OTP1A = OTQ1  + SST;                   // [B,60,60]
static constexpr size_t OTP2  = OTP1A + (size_t)B*LD;          // [B,30,28,28]
static constexpr size_t OV1S  = OTP2  + (size_t)B*30*LP;
static constexpr size_t OI1S  = OV1S  + SST2;
static constexpr size_t OTQ2S = OI1S  + SST2;
static constexpr size_t OZEND = OTQ2S + SST2;                  // end of zero region 1
static constexpr size_t OTP1B = OZEND;                         // [B,60,60] pong
static constexpr size_t OZ3   = OTP1B + (size_t)B*LD;          // [B,30,28,28] (zeroed!)
static constexpr size_t OZ4S  = OZ3   + (size_t)B*30*LP;       // reclaimed region (ping-pong bufs)
static constexpr size_t OE2P  = OZ4S  + SST2;                  // part buffer B (96000 fits in 150000)
static constexpr size_t OE2M  = OE2P  + 75000;
static constexpr size_t OP1   = OE2M  + 75000;                 // part buffer A [30][50][64]
static constexpr size_t OG    = OP1   + 96000;                 // [T][3200]
static constexpr size_t OHH   = OG    + (size_t)T*3200;        // [T][500]
static constexpr size_t OW2P  = OHH   + (size_t)T*500;         // w2 buffer A [100][30][28]
static constexpr size_t OCNZ  = OW2P  + 84000;                 // cnz4 buffer A int[960][4]
static constexpr size_t OTOT  = OCNZ  + 3840;
// MFMA correlation buffers:
static constexpr size_t OEPP  = OTOT;                          // E2P partials [32][75000] f32
static constexpr size_t OEMP  = OEPP + (size_t)B*75000;        // E2M partials [32][75000] f32
static constexpr size_t OPHI  = OEMP + (size_t)B*75000;        // tp2 hi plane A [B][30][784] u16
static constexpr size_t OPLO  = OPHI + 376320;                 // tp2 lo plane A
static constexpr size_t OPZ3  = OPLO + 376320;                 // z3 bf16 plane A
static constexpr size_t OQZ4  = OPZ3 + 376320;                 // z4 bf16 [B][112][576] u16
static constexpr size_t OQHI  = OQZ4 + 1032192;                // tq2 hi plane
static constexpr size_t OQLO  = OQHI + 1032192;                // tq2 lo plane
static constexpr size_t OTOT2 = OQLO + 1032192;
// sticky zero-tracking flags:
static constexpr size_t OQZF  = OTOT2;                         // (unused now - registers)
static constexpr size_t OPZF  = OQZF + 512;                    // int[960]  plane-zero per (b,o)
static constexpr size_t OSZF  = OPZF + 960;                    // int[416]  conv2-state-zero per (b,jg)
static constexpr size_t OEAF  = OSZF + 416;                    // int[480]  E-active per (b,cg)
static constexpr size_t OTOT3 = OEAF + 480;
// ping-pong B buffers carved out of the dead OZ4S region (size SST2 = 1,916,928 floats):
static constexpr size_t OPL2H = OZ4S;                          // tp2 hi plane B
static constexpr size_t OPL2L = OPL2H + 376320;                // tp2 lo plane B
static constexpr size_t OPL2Z = OPL2L + 376320;                // z3 bf16 plane B
static constexpr size_t OW2B  = OPL2Z + 376320;                // w2 buffer B (84000)
static constexpr size_t OW1B  = OW2B + 84000;                  // w1 buffer B (1500)
static constexpr size_t OCNZB = OW1B + 1500;                   // cnz4 buffer B (3840)
static constexpr size_t OBAR  = OCNZB + 3840;                  // grid barrier counter (16)
static constexpr size_t OZ4SEND = OBAR + 16;
static_assert(OZ4SEND <= OZ4S + SST2, "overlay overflow");

struct DK { float v[25]; };

typedef __attribute__((ext_vector_type(8))) short bfx8;
typedef __attribute__((ext_vector_type(4))) float f32x4;

static __device__ __forceinline__ unsigned short f2bf(float f) {
    unsigned u = __float_as_uint(f);
    return (unsigned short)((u + 0x7FFFu + ((u >> 16) & 1u)) >> 16);
}
static __device__ __forceinline__ float bf2f(unsigned short h) {
    return __uint_as_float(((unsigned)h) << 16);
}

// device-scope grid barrier: monotonic counter, all 256 blocks execute identical counts.
// __syncthreads drains each thread's vmem (vmcnt 0 before s_barrier); tid0's
// __threadfence (agent scope) flushes/invalidates the CU/XCD caches cache-wide.
static __device__ __forceinline__ void gbar(unsigned int* bar, unsigned int target) {
    __syncthreads();
    if (threadIdx.x == 0) {
        __threadfence();
        atomicAdd(bar, 1u);
        while (__hip_atomic_load(bar, __ATOMIC_ACQUIRE, __HIP_MEMORY_SCOPE_AGENT) < target)
            __builtin_amdgcn_s_sleep(2);
        __threadfence();
    }
    __syncthreads();
}

// STDP w1 pair update (both on/off channel entries share the same part sums).
static __device__ __forceinline__ float2 w1pair(const float* w1cur, const float* pprev,
                                                int o, int pp, int t) {
    float wa = w1cur[o*50 + pp], wb = w1cur[o*50 + 25 + pp];
    if (t > 0) {
        float EpS = 0.f, EmS = 0.f;
        for (int s = 0; s < 64; ++s) {
            EpS += pprev[((size_t)(o*50 + pp) << 6) + s];
            EmS += pprev[((size_t)(o*50 + 25 + pp) << 6) + s];
        }
        wa = fminf(fmaxf(wa + 0.004f*fmaxf(1.f-wa,0.f)*EpS - 0.003f*fmaxf(wa,0.f)*EmS, 0.f), 1.f);
        wb = fminf(fmaxf(wb + 0.004f*fmaxf(1.f-wb,0.f)*(-EpS) - 0.003f*fmaxf(wb,0.f)*(-EmS), 0.f), 1.f);
    }
    return make_float2(wa, wb);
}

// STDP w2 update for one element; e = (j*30+c)*25+p25.
static __device__ __forceinline__ float w2eff(float w, size_t e, int cg,
        const int* eact, const float* EPp, const float* EMp) {
    float ep = 0.f, em = 0.f; int any = 0;
    for (int bb = 0; bb < 32; ++bb) {
        if (eact[bb*15 + cg]) {
            any = 1;
            ep += EPp[(size_t)bb*75000 + e];
            em += EMp[(size_t)bb*75000 + e];
        }
    }
    if (!any) return w;
    float dwp = 0.004f * fmaxf(1.0f - w, 0.0f) * ep;
    float dwm = 0.003f * fmaxf(w, 0.0f) * em;
    return fminf(fmaxf(w + dwp - dwm, 0.0f), 1.0f);
}

union SMEM {
    struct {
        float xsh[36*64];
        float zsh[32*60];
        float tsh[32*60];
        float red[700];
        float wd[100];
        int   sflags[8];
    } f;
    struct {
        unsigned short sB[2*3*5*672 + 704];   // [cc:2][plane:3][dx:5][672] + zero block
        float sG[100];
        int sAnyI;
    } c;
    struct {
        float spre[LP];
        int sjany[8];
        int sany;
        int cgany[15];
    } v;
};

// ================= persistent T-loop kernel: 256 blocks x 448 threads =================
__global__ __launch_bounds__(448) void k_loop(
        const float* __restrict__ x, const float* __restrict__ b1,
        const float* __restrict__ b2, float* ws, DK dk) {
    __shared__ __attribute__((aligned(16))) SMEM sm;
    const int blk = blockIdx.x, tid = threadIdx.x;
    const int og = blk & 7;

    float* tq1g = ws + OTQ1;
    float* z3g  = ws + OZ3;
    float* tp2g = ws + OTP2;
    int* pzf = (int*)(ws + OPZF);
    int* szf = (int*)(ws + OSZF);
    int* eact = (int*)(ws + OEAF);
    unsigned int* bar = (unsigned int*)(ws + OBAR);
    float* EPp = ws + OEPP;
    float* EMp = ws + OEMP;
    unsigned short* z4bg = (unsigned short*)(ws + OQZ4);
    unsigned short* tqhg = (unsigned short*)(ws + OQHI);
    unsigned short* tqlg = (unsigned short*)(ws + OQLO);

    const float bias = b1[0] - b2[0];

    // persistent register state: v0/i0 for the 2 owned front tiles (exactly replaces
    // the old slot-major global arrays; same arithmetic, zero traffic).
    float v0r[28], i0r[28];
    #pragma unroll
    for (int k = 0; k < 28; ++k) { v0r[k] = 0.f; i0r[k] = 0.f; }
    bool qz0 = true, qz1 = true;   // tq1 sticky-zero per owned tile

    unsigned int bt = 0;

    #pragma unroll 1
    for (int t = 0; t < T; ++t) {
        const float* tp1r = ws + ((t & 1) ? OTP1B : OTP1A);
        float*       tp1w = ws + ((t & 1) ? OTP1A : OTP1B);
        const float* w1cur = ws + ((t & 1) ? OW1B : OW1);
        float*       w1nxt = ws + ((t & 1) ? OW1 : OW1B);
        float*       partW = ws + ((t & 1) ? OE2P : OP1);
        const float* pprev = ws + ((t & 1) ? OP1 : OE2P);
        int*         cnzC  = (int*)(ws + ((t & 1) ? OCNZB : OCNZ));
        const int*   cnzP  = (const int*)(ws + ((t & 1) ? OCNZ : OCNZB));
        unsigned short* uhiW = (unsigned short*)(ws + ((t & 1) ? OPL2H : OPHI));
        unsigned short* uloW = (unsigned short*)(ws + ((t & 1) ? OPL2L : OPLO));
        unsigned short* uz3W = (unsigned short*)(ws + ((t & 1) ? OPL2Z : OPZ3));
        const unsigned short* uhiR = (const unsigned short*)(ws + ((t & 1) ? OPHI : OPL2H));
        const unsigned short* uloR = (const unsigned short*)(ws + ((t & 1) ? OPLO : OPL2L));
        const unsigned short* uz3R = (const unsigned short*)(ws + ((t & 1) ? OPZ3 : OPL2Z));

        // ================== PHASE F: front(t)  ||  corr(t-1) ==================
        // inline w1 update (every block recomputes its wd; blocks 0-3 persist full w1)
        if (tid < 100) {
            int oo2 = tid / 25, pp = tid % 25;
            int o2 = og*4 + oo2; if (o2 > 29) o2 = 29;
            float2 wp = w1pair(w1cur, pprev, o2, pp, t);
            sm.f.wd[tid] = wp.x - wp.y;
        }
        if (blk < 4) {
            int e = blk*448 + tid;
            if (e < 1500) {
                int o = e/50, r = e%50, ch = r/25, pp = r%25;
                float2 wp = w1pair(w1cur, pprev, o, pp, t);
                w1nxt[e] = ch ? wp.y : wp.x;
            }
        }

        #pragma unroll
        for (int li = 0; li < 2; ++li) {
            const int lb = blk + li*256;
            const int by = lb >> 3;
            const int b = by >> 1, yh = by & 1, y0 = yh*28;
            __syncthreads();
            {
                const float4* xs = (const float4*)(x + ((size_t)t*B + b)*4096) + y0*16;
                const float4* ts = (const float4*)(tp1r + (size_t)b*LD) + y0*15;
                for (int i2 = tid; i2 < 576; i2 += 448) ((float4*)sm.f.xsh)[i2] = xs[i2];
                for (int i2 = tid; i2 < 480; i2 += 448) ((float4*)sm.f.tsh)[i2] = ts[i2];
            }
            if (tid < 8) sm.f.sflags[tid] = 0;
            __syncthreads();
            // DoG + tp1 trace (og==0 persists tp1)
            for (int idx = tid; idx < 1920; idx += 448) {
                int lr = idx / 60, c = idx % 60;
                float a = 0.f;
                #pragma unroll
                for (int kh = 0; kh < 5; kh++)
                    #pragma unroll
                    for (int kw = 0; kw < 5; kw++)
                        a = fmaf(dk.v[kh*5+kw], sm.f.xsh[(lr+kh)*64 + c + kw], a);
                float zv = a + bias;
                sm.f.zsh[idx] = zv;
                float tp = sm.f.tsh[idx];
                tp = tp + DTTR*(zv - tp);
                sm.f.tsh[idx] = tp;
                if (og == 0) tp1w[(size_t)b*LD + (y0 + lr)*60 + c] = tp;
            }
            __syncthreads();
            int oo = tid & 3, xq = (tid >> 2) & 3, yv = tid >> 4;
            int o = og*4 + oo, xx0 = xq*14;
            bool valid = (o < 30);
            float zn[14], tn[14];
            float zs = 0.f, qs = 0.f;
            bool anym = false;
            bool qzold = (li == 0) ? qz0 : qz1;
            if (valid) {
                float acc[14];
                #pragma unroll
                for (int k = 0; k < 14; k++) acc[k] = 0.f;
                #pragma unroll
                for (int kh = 0; kh < 5; kh++) {
                    float rr[18];
                    const float2* r2 = (const float2*)&sm.f.zsh[(yv+kh)*HD + xx0];
                    #pragma unroll
                    for (int i = 0; i < 9; i++) ((float2*)rr)[i] = r2[i];
                    #pragma unroll
                    for (int kw = 0; kw < 5; kw++) {
                        float w = sm.f.wd[oo*25 + kh*5 + kw];
                        #pragma unroll
                        for (int k = 0; k < 14; k++) acc[k] = fmaf(w, rr[k+kw], acc[k]);
                    }
                }
                // LIF0 (registers) + tq1 (global, sticky-zero gated)
                float2* tq1p2 = (float2*)tq1g;
                size_t sb = ((size_t)((b*8 + og)*2 + yh)*7)*448 + tid;
                #pragma unroll
                for (int i = 0; i < 7; i++) {
                    float2 t2;
                    if (qzold) { t2.x = 0.f; t2.y = 0.f; }
                    else t2 = tq1p2[sb + (size_t)i*448];
                    float2 tn2;
                    bool sp = false;
                    #pragma unroll
                    for (int k = 0; k < 2; k++) {
                        int e = i*2 + k;
                        float vv = v0r[li*14 + e], cc = i0r[li*14 + e];
                        float tt = k ? t2.y : t2.x;
                        float vd = vv + DTMEM*(cc - vv);
                        float z = (vd > 15.0f) ? 1.0f : 0.0f;
                        v0r[li*14 + e] = (1.0f - z)*vd;
                        i0r[li*14 + e] = (cc - DTSYN*cc) + acc[e];
                        float tq = tt + DTTR*(z - tt);
                        if (k) tn2.y = tq; else tn2.x = tq;
                        zn[e] = z; tn[e] = tq;
                        sp = sp || (z != 0.f);
                    }
                    if (!qzold || sp) tq1p2[sb + (size_t)i*448] = tn2;
                }
                #pragma unroll
                for (int k = 0; k < 14; k++) { zs += zn[k]; qs += tn[k]; }
                float mx[7];
                #pragma unroll
                for (int k = 0; k < 7; k++) mx[k] = fmaxf(zn[2*k], zn[2*k+1]);
                #pragma unroll
                for (int k = 0; k < 7; k++) {
                    float pm = __shfl_xor(mx[k], 16, 64);
                    mx[k] = fmaxf(mx[k], pm);
                }
                if ((yv & 1) == 0) {
                    int pzOld = pzf[b*30 + o];
                    int py = yh*14 + (yv >> 1);
                    size_t pb = ((size_t)(b*30 + o)*HP + py)*HP + xq*7;
                    #pragma unroll
                    for (int k = 0; k < 7; k++) {
                        float m = mx[k];
                        anym = anym || (m != 0.f);
                        if (!pzOld || m != 0.f) {
                            z3g[pb + k] = m;
                            float tpv = pzOld ? 0.f : tp2g[pb + k];
                            float tnew = tpv + DTTR*(m - tpv);
                            tp2g[pb + k] = tnew;
                            unsigned short h = f2bf(tnew);
                            uhiW[pb + k] = h;
                            uloW[pb + k] = f2bf(tnew - bf2f(h));
                            uz3W[pb + k] = (m != 0.f) ? (unsigned short)0x3F80 : (unsigned short)0;
                        }
                    }
                }
            }
            if (anym) atomicOr(&sm.f.sflags[oo*2 + (xq >> 1)], 1);
            int lane = tid & 63, wave = tid >> 6;
            // pass 1: minus correlation (unfold(z0) x tq1_new)
            {
                float a[25];
                #pragma unroll
                for (int pq = 0; pq < 25; pq++) a[pq] = 0.f;
                if (valid && qs != 0.f) {
                    #pragma unroll
                    for (int kh = 0; kh < 5; kh++) {
                        float rr[18];
                        const float2* r2 = (const float2*)&sm.f.zsh[(yv+kh)*HD + xx0];
                        #pragma unroll
                        for (int i = 0; i < 9; i++) ((float2*)rr)[i] = r2[i];
                        #pragma unroll
                        for (int kw = 0; kw < 5; kw++)
                            #pragma unroll
                            for (int k = 0; k < 14; k++)
                                a[kh*5+kw] = fmaf(rr[k+kw], tn[k], a[kh*5+kw]);
                    }
                }
                #pragma unroll
                for (int q = 0; q < 25; q++) {
                    float v = a[q];
                    v += __shfl_xor(v, 4, 64);
                    v += __shfl_xor(v, 8, 64);
                    v += __shfl_xor(v, 16, 64);
                    v += __shfl_xor(v, 32, 64);
                    if (lane < 4) sm.f.red[wave*100 + lane*25 + q] = v;
                }
            }
            __syncthreads();
            int anyblk = sm.f.sflags[0]|sm.f.sflags[1]|sm.f.sflags[2]|sm.f.sflags[3]|
                         sm.f.sflags[4]|sm.f.sflags[5]|sm.f.sflags[6]|sm.f.sflags[7];
            if (tid < 100) {
                int oo2 = tid / 25, q = tid % 25;
                float s = 0.f;
                #pragma unroll
                for (int w = 0; w < 7; w++) s += sm.f.red[w*100 + oo2*25 + q];
                int o2 = og*4 + oo2;
                if (o2 < 30) partW[((size_t)(o2*50 + 25 + q) << 6) + b*2 + yh] = s;
            }
            if (tid < 8) {
                int o2 = og*4 + (tid >> 1);
                if (o2 < 30) cnzC[(b*30 + o2)*4 + yh*2 + (tid & 1)] = sm.f.sflags[tid];
            }
            if (li == 0) qz0 = qzold && (anyblk == 0);
            else         qz1 = qzold && (anyblk == 0);
            __syncthreads();
            // pass 2: plus correlation (unfold(tp1_new) x z2)
            {
                float a[25];
                #pragma unroll
                for (int pq = 0; pq < 25; pq++) a[pq] = 0.f;
                if (valid && zs != 0.f) {
                    #pragma unroll
                    for (int kh = 0; kh < 5; kh++) {
                        float rr[18];
                        const float2* r2 = (const float2*)&sm.f.tsh[(yv+kh)*HD + xx0];
                        #pragma unroll
                        for (int i = 0; i < 9; i++) ((float2*)rr)[i] = r2[i];
                        #pragma unroll
                        for (int kw = 0; kw < 5; kw++)
                            #pragma unroll
                            for (int k = 0; k < 14; k++)
                                a[kh*5+kw] = fmaf(rr[k+kw], zn[k], a[kh*5+kw]);
                    }
                }
                #pragma unroll
                for (int q = 0; q < 25; q++) {
                    float v = a[q];
                    v += __shfl_xor(v, 4, 64);
                    v += __shfl_xor(v, 8, 64);
                    v += __shfl_xor(v, 16, 64);
                    v += __shfl_xor(v, 32, 64);
                    if (lane < 4) sm.f.red[wave*100 + lane*25 + q] = v;
                }
            }
            __syncthreads();
            if (tid < 100) {
                int oo2 = tid / 25, q = tid % 25;
                float s = 0.f;
                #pragma unroll
                for (int w = 0; w < 7; w++) s += sm.f.red[w*100 + oo2*25 + q];
                int o2 = og*4 + oo2;
                if (o2 < 30) partW[((size_t)(o2*50 + q) << 6) + b*2 + yh] = s;
            }
        }

        // ---- corr(t-1): MFMA STDP correlations into per-b E partials ----
        if (t >= 1) {
            const float* gfl = ws + OG + (size_t)(t-1)*3200;
            #pragma unroll 1
            for (int ci = 0; ci < 2; ++ci) {
                int cb = blk + ci*256;
                bool cok = (cb < 480);
                int b = cb & 31, cg = cb >> 5; if (cg > 14) cg = 14;
                __syncthreads();
                if (tid == 0) sm.c.sAnyI = 0;
                for (int i2 = tid; i2 < 704; i2 += 448) sm.c.sB[20160 + i2] = 0;
                __syncthreads();
                if (cok && tid < 100) {
                    float gv = gfl[b*100 + tid];
                    sm.c.sG[tid] = gv;
                    if (gv != 0.f) atomicOr(&sm.c.sAnyI, 1);
                }
                bool cA0 = false, cA1 = false;
                if (cok) {
                    const int* cz0 = cnzP + (b*30 + cg*2)*4;
                    const int* cz1 = cnzP + (b*30 + cg*2 + 1)*4;
                    cA0 = (cz0[0]|cz0[1]|cz0[2]|cz0[3]) != 0;
                    cA1 = (cz1[0]|cz1[1]|cz1[2]|cz1[3]) != 0;
                }
                __syncthreads();
                bool m0 = cok && (sm.c.sAnyI != 0);
                bool m1any = cA0 || cA1;
                bool activeB = m0 || m1any;
                if (cok && tid == 0) eact[b*15 + cg] = activeB ? 1 : 0;
                if (activeB) {
                    for (int cc = 0; cc < 2; cc++) {
                        int c = cg*2 + cc;
                        bool cAc = cc ? cA1 : cA0;
                        for (int pl = 0; pl < 3; pl++) {
                            bool need = (pl < 2) ? m0 : cAc;
                            if (!need) continue;
                            const unsigned short* src =
                                ((pl == 0) ? uhiR : (pl == 1) ? uloR : uz3R) + (size_t)(b*30 + c)*784;
                            for (int idx = tid; idx < 784; idx += 448) {
                                unsigned short v = src[idx];
                                int r = idx / 28, col = idx - r*28;
                                int base = ((cc*3 + pl)*5)*672 + r*24;
                                #pragma unroll
                                for (int dx = 0; dx < 5; dx++) {
                                    int xx = col - dx;
                                    if (xx >= 0 && xx < 24) sm.c.sB[base + dx*672 + xx] = v;
                                }
                            }
                        }
                    }
                    __syncthreads();
                    int lane = tid & 63, mt = tid >> 6;   // 7 waves = 7 M-tiles
                    int jr = mt*16 + (lane & 15);
                    float gv = (jr < 100) ? sm.c.sG[jr] : 0.f;
                    bool m0mt = m0 && (__any(gv != 0.f) != 0);
                    int g8 = (lane >> 4) * 8;
                    size_t arow = ((size_t)b*112 + (size_t)mt*16 + (lane & 15))*576 + g8;
                    int bOff[2][3][2];
                    #pragma unroll
                    for (int cc = 0; cc < 2; cc++)
                        #pragma unroll
                        for (int pl = 0; pl < 3; pl++)
                            #pragma unroll
                            for (int n = 0; n < 2; n++) {
                                int p25 = n*16 + (lane & 15);
                                int off;
                                if (p25 < 25) {
                                    int dy = p25 / 5, dx = p25 - dy*5;
                                    off = (((cc*3 + pl)*5 + dx)*672 + dy*24)*2;
                                } else off = 40320;
                                bOff[cc][pl][n] = off;
                            }
                    f32x4 C0[2][2], C1[2][2];
                    #pragma unroll
                    for (int cc = 0; cc < 2; cc++)
                        #pragma unroll
                        for (int n = 0; n < 2; n++) {
                            C0[cc][n] = (f32x4){0.f,0.f,0.f,0.f};
                            C1[cc][n] = (f32x4){0.f,0.f,0.f,0.f};
                        }
                    const char* sBb = (const char*)sm.c.sB;
                    #pragma unroll 1
                    for (int ks = 0; ks < 18; ks++) {
                        int common = (ks*32 + g8)*2;
                        bfx8 a0 = {}, ah = {}, al = {};
                        size_t off = arow + (size_t)ks*32;
                        if (m0mt) a0 = *(const bfx8*)(z4bg + off);
                        if (m1any) {
                            ah = *(const bfx8*)(tqhg + off);
                            al = *(const bfx8*)(tqlg + off);
                        }
                        #pragma unroll
                        for (int cc = 0; cc < 2; cc++) {
                            bool cAc = cc ? cA1 : cA0;
                            #pragma unroll
                            for (int n = 0; n < 2; n++) {
                                if (m0) {
                                    bfx8 Bh = *(const bfx8*)(sBb + bOff[cc][0][n] + common);
                                    bfx8 Bl = *(const bfx8*)(sBb + bOff[cc][1][n] + common);
                                    if (m0mt) {
                                        C0[cc][n] = __builtin_amdgcn_mfma_f32_16x16x32_bf16(a0, Bh, C0[cc][n], 0, 0, 0);
                                        C0[cc][n] = __builtin_amdgcn_mfma_f32_16x16x32_bf16(a0, Bl, C0[cc][n], 0, 0, 0);
                                    }
                                }
                                if (cAc) {
                                    bfx8 Bz = *(const bfx8*)(sBb + bOff[cc][2][n] + common);
                                    C1[cc][n] = __builtin_amdgcn_mfma_f32_16x16x32_bf16(ah, Bz, C1[cc][n], 0, 0, 0);
                                    C1[cc][n] = __builtin_amdgcn_mfma_f32_16x16x32_bf16(al, Bz, C1[cc][n], 0, 0, 0);
                                }
                            }
                        }
                    }
                    size_t eb = (size_t)b * 75000;
                    #pragma unroll
                    for (int cc = 0; cc < 2; cc++) {
                        int c = cg*2 + cc;
                        #pragma unroll
                        for (int n = 0; n < 2; n++) {
                            int p25 = n*16 + (lane & 15);
                            if (p25 >= 25) continue;
                            #pragma unroll
                            for (int q = 0; q < 4; q++) {
                                int j = mt*16 + (lane >> 4)*4 + q;
                                if (j < 100) {
                                    size_t eidx = eb + ((size_t)j*30 + c)*25 + p25;
                                    EPp[eidx] = C0[cc][n][q];
                                    EMp[eidx] = C1[cc][n][q];
                                }
                            }
                        }
                    }
                }
            }
        }

        bt += 256; gbar(bar, bt);

        // ================== PHASE C: conv2(t) with inline w2 update ==================
        {
            const float* w2cur = ws + ((t & 1) ? OW2B : OW2P);
            float*       w2nxt = ws + ((t & 1) ? OW2P : OW2B);
            float* g_t = ws + OG + (size_t)t*3200;
            // w2 persist (spread across all blocks; exact copy when inactive)
            {
                int e = blk*448 + tid;
                if (e < 75000) {
                    int j = e/750, r = e%750, c = r/25, p25 = r%25;
                    size_t f = ((size_t)j*30 + c)*28 + p25;
                    float w = w2cur[f];
                    if (t > 0) w = w2eff(w, (size_t)(j*30 + c)*25 + p25, c >> 1, eact, EPp, EMp);
                    w2nxt[f] = w;
                }
            }
            float4* v1p = (float4*)(ws + OV1S);
            float4* i1p = (float4*)(ws + OI1S);
            float4* t2p = (float4*)(ws + OTQ2S);
            #pragma unroll 1
            for (int ci = 0; ci < 2; ++ci) {
                int cb2 = blk + ci*256;
                if (cb2 >= 416) continue;
                int jg = cb2 % 13, b = cb2 / 13;
                int jb0 = jg*8;
                __syncthreads();
                if (tid < 8) sm.v.sjany[tid] = 0;
                if (tid == 0) sm.v.sany = 0;
                if (tid < 15) {
                    int a = 0;
                    if (t > 0) for (int bb = 0; bb < 32; ++bb) a |= eact[bb*15 + tid];
                    sm.v.cgany[tid] = a;
                }
                __syncthreads();
                if (tid < 120 && cnzC[b*120 + tid]) atomicOr(&sm.v.sany, 1);
                __syncthreads();
                if (jg == 0 && tid < 30) {
                    const int* cz = cnzC + (b*30 + tid)*4;
                    if ((cz[0]|cz[1]|cz[2]|cz[3]) != 0) pzf[b*30 + tid] = 0;
                }
                int szv = szf[b*13 + jg];
                if (szv && !sm.v.sany) {
                    if (tid < 8 && jb0 + tid < 100) g_t[b*100 + jb0 + tid] = 0.f;
                    continue;
                }
                int jp = tid & 3;
                int j0 = jb0 + jp*2;
                int yv = tid >> 3, xx0 = ((tid >> 2) & 1)*12;
                int ja = (j0 < 100) ? j0 : 99;
                int jbb = (j0+1 < 100) ? j0+1 : 99;
                bool run = (tid < 192);
                float acc0[12], acc1[12];
                #pragma unroll
                for (int xq = 0; xq < 12; xq++) { acc0[xq] = 0.f; acc1[xq] = 0.f; }
                #pragma unroll 1
                for (int c = 0; c < 30; c++) {
                    const int* cz = cnzC + (b*30 + c)*4;
                    bool act = (cz[0] | cz[1] | cz[2] | cz[3]) != 0;
                    __syncthreads();
                    if (act) {
                        const float4* src = (const float4*)(z3g + (size_t)(b*30 + c)*LP);
                        for (int i2 = tid; i2 < 196; i2 += 448) ((float4*)sm.v.spre)[i2] = src[i2];
                    }
                    __syncthreads();
                    if (!act) continue;
                    if (run) {
                        float wa[28], wb[28];
                        #pragma unroll
                        for (int i = 0; i < 7; i++) {
                            ((float4*)wa)[i] = ((const float4*)(w2cur + ((size_t)ja*30 + c)*28))[i];
                            ((float4*)wb)[i] = ((const float4*)(w2cur + ((size_t)jbb*30 + c)*28))[i];
                        }
                        if (t > 0 && sm.v.cgany[c >> 1]) {
                            #pragma unroll
                            for (int p25 = 0; p25 < 25; p25++) {
                                wa[p25] = w2eff(wa[p25], (size_t)(ja*30 + c)*25 + p25, c >> 1, eact, EPp, EMp);
                                wb[p25] = w2eff(wb[p25], (size_t)(jbb*30 + c)*25 + p25, c >> 1, eact, EPp, EMp);
                            }
                        }
                        #pragma unroll
                        for (int kh = 0; kh < 5; kh++) {
                            float rr[16];
                            const float4* r4 = (const float4*)&sm.v.spre[(yv+kh)*HP + xx0];
                            #pragma unroll
                            for (int i = 0; i < 4; i++) ((float4*)rr)[i] = r4[i];
                            #pragma unroll
                            for (int kw = 0; kw < 5; kw++) {
                                float w0 = wa[kh*5+kw], w1v = wb[kh*5+kw];
                                #pragma unroll
                                for (int xq = 0; xq < 12; xq++) {
                                    acc0[xq] = fmaf(w0, rr[xq+kw], acc0[xq]);
                                    acc1[xq] = fmaf(w1v, rr[xq+kw], acc1[xq]);
                                }
                            }
                        }
                    }
                }
                bool spk0 = false, spk1 = false;
                if (run) {
                    size_t sb2 = ((size_t)(b*13 + jg)*6)*192 + tid;
                    #pragma unroll
                    for (int jj = 0; jj < 2; jj++) {
                        bool anyspk = false;
                        int j_eff = jj ? jbb : ja;
                        #pragma unroll
                        for (int i = 0; i < 3; i++) {
                            size_t si = sb2 + (size_t)(jj*3 + i)*192;
                            float4 v4 = v1p[si];
                            float4 c4 = i1p[si];
                            float4 t4 = t2p[si];
                            float4 vn, in, zn4, tn4;
                            float* vp=(float*)&v4; float* cp=(float*)&c4; float* tp=(float*)&t4;
                            float* vnp=(float*)&vn; float* inp=(float*)&in; float* znp=(float*)&zn4; float* tnp=(float*)&tn4;
                            #pragma unroll
                            for (int k = 0; k < 4; k++) {
                                float a = jj ? acc1[i*4+k] : acc0[i*4+k];
                                float vd = vp[k] + DTMEM*(cp[k] - vp[k]);
                                float z = (vd > 10.0f) ? 1.0f : 0.0f;
                                vnp[k] = (1.0f - z)*vd;
                                inp[k] = (cp[k] - DTSYN*cp[k]) + 10.0f*a;
                                znp[k] = z;
                                tnp[k] = tp[k] + DTTR*(z - tp[k]);
                                anyspk = anyspk || (z != 0.f);
                            }
                            v1p[si] = vn;
                            i1p[si] = in;
                            t2p[si] = tn4;
                            size_t pb2 = ((size_t)b*112 + j_eff)*576 + (size_t)(yv*24 + xx0 + i*4);
                            ushort4 zb, hb, lb4;
                            unsigned short h;
                            zb.x = (znp[0]!=0.f)?(unsigned short)0x3F80:(unsigned short)0;
                            zb.y = (znp[1]!=0.f)?(unsigned short)0x3F80:(unsigned short)0;
                            zb.z = (znp[2]!=0.f)?(unsigned short)0x3F80:(unsigned short)0;
                            zb.w = (znp[3]!=0.f)?(unsigned short)0x3F80:(unsigned short)0;
                            h = f2bf(tnp[0]); hb.x = h; lb4.x = f2bf(tnp[0] - bf2f(h));
                            h = f2bf(tnp[1]); hb.y = h; lb4.y = f2bf(tnp[1] - bf2f(h));
                            h = f2bf(tnp[2]); hb.z = h; lb4.z = f2bf(tnp[2] - bf2f(h));
                            h = f2bf(tnp[3]); hb.w = h; lb4.w = f2bf(tnp[3] - bf2f(h));
                            *(ushort4*)(z4bg + pb2) = zb;
                            *(ushort4*)(tqhg + pb2) = hb;
                            *(ushort4*)(tqlg + pb2) = lb4;
                        }
                        if (jj == 0) spk0 = anyspk; else spk1 = anyspk;
                    }
                    if (spk0 && j0 < 100) atomicOr(&sm.v.sjany[jp*2], 1);
                    if (spk1 && j0+1 < 100) atomicOr(&sm.v.sjany[jp*2+1], 1);
                }
                __syncthreads();
                if (tid < 8 && jb0 + tid < 100) g_t[b*100 + jb0 + tid] = sm.v.sjany[tid] ? 1.f : 0.f;
                if (tid == 0 && szv) szf[b*13 + jg] = 0;
            }
        }

        bt += 256; gbar(bar, bt);
    }
}

// ================= k_prep: build padded w2p from INPUT w2 + init flags =================
__global__ void k_prep(const float* __restrict__ w2, float* __restrict__ w2p,
                       int* __restrict__ pzf, int* __restrict__ szf,
                       int* __restrict__ eact) {
    int e = blockIdx.x*blockDim.x + threadIdx.x;
    if (e < 75000) {
        int j = e / 750, r = e % 750, c = r / 25, p = r % 25;
        w2p[((size_t)j*30 + c)*28 + p] = w2[e];
    }
    if (e < 960) pzf[e] = 1;
    if (e < 416) szf[e] = 1;
    if (e < 480) eact[e] = 0;
}

// ================= k_fc1b: batched fc1, grid (500 n, 4 t-quarters) =================
__global__ __launch_bounds__(256) void k_fc1b(
        const float* __restrict__ g_all, const float* __restrict__ fcw,
        const float* __restrict__ fcb, float* __restrict__ h_all) {
    __shared__ float red[8][4];
    int n = blockIdx.x, by = blockIdx.y, tid = threadIdx.x;
    const float4* w4 = (const float4*)(fcw + (size_t)n*3200);
    float4 wreg[4];
    #pragma unroll
    for (int i = 0; i < 4; i++) {
        int k = tid + 256*i;
        if (k < 800) wreg[i] = w4[k];
    }
    float accs[8];
    #pragma unroll
    for (int tt = 0; tt < 8; tt++) accs[tt] = 0.f;
    #pragma unroll 1
    for (int tt = 0; tt < 8; tt++) {
        int t = by*8 + tt;
        const float4* g4 = (const float4*)(g_all + (size_t)t*3200);
        float a = 0.f;
        #pragma unroll
        for (int i = 0; i < 4; i++) {
            int k = tid + 256*i;
            if (k < 800) {
                float4 gv = g4[k];
                a = fmaf(gv.x, wreg[i].x, a);
                a = fmaf(gv.y, wreg[i].y, a);
                a = fmaf(gv.z, wreg[i].z, a);
                a = fmaf(gv.w, wreg[i].w, a);
            }
        }
        accs[tt] = a;
    }
    int lane = tid & 63, wid = tid >> 6;
    #pragma unroll
    for (int tt = 0; tt < 8; tt++) {
        float v = accs[tt];
        #pragma unroll
        for (int s = 32; s >= 1; s >>= 1) v += __shfl_down(v, s, 64);
        if (lane == 0) red[tt][wid] = v;
    }
    __syncthreads();
    if (tid < 8)
        h_all[(size_t)(by*8 + tid)*500 + n] =
            red[tid][0] + red[tid][1] + red[tid][2] + red[tid][3] + fcb[n];
}

// ================= k_head_all: LIF2 + LI readout =================
__global__ __launch_bounds__(640) void k_head_all(
        const float* __restrict__ h_all, const float* __restrict__ outw,
        float* __restrict__ out) {
    __shared__ float spk[500];
    __shared__ float vout[10];
    int tid = threadIdx.x;
    int wid = tid >> 6, lane = tid & 63;
    float v2r = 0.f, i2r = 0.f;
    float vor = 0.f, ior = 0.f;
    #pragma unroll 1
    for (int t = 0; t < 32; t++) {
        if (tid < 500) {
            float cur = i2r;
            float vd = v2r + DTMEM*(cur - v2r);
            float z = (vd > 1.0f) ? 1.0f : 0.0f;
            v2r = (1.0f - z)*vd;
            i2r = (cur - DTSYN*cur) + h_all[t*500 + tid];
            spk[tid] = z;
        }
        __syncthreads();
        float acc = 0.f;
        for (int n = lane; n < 500; n += 64)
            acc = fmaf(spk[n], outw[wid*500 + n], acc);
        #pragma unroll
        for (int s = 32; s >= 1; s >>= 1) acc += __shfl_down(acc, s, 64);
        if (lane == 0) {
            float ij = ior + acc;
            float vn = vor + DTMEM*(ij - vor);
            ior = ij - DTSYN*ij;
            vor = vn;
            vout[wid] = vn;
        }
        __syncthreads();
        if (tid < 320) out[(size_t)t*320 + tid] = vout[tid % 10];
        __syncthreads();
    }
}

// ---------------- launcher ----------------
extern "C" void kernel_launch(void* const* d_in, const int* in_sizes, int n_in,
                              void* d_out, int out_size, void* d_ws, size_t ws_size,
                              hipStream_t stream) {
    const float* x    = (const float*)d_in[0];
    const float* b1   = (const float*)d_in[1];
    const float* b2   = (const float*)d_in[2];
    const float* w1   = (const float*)d_in[3];
    const float* w2   = (const float*)d_in[4];
    const float* fcw  = (const float*)d_in[5];
    const float* fcb  = (const float*)d_in[6];
    const float* outw = (const float*)d_in[7];
    float* ws  = (float*)d_ws;
    float* out = (float*)d_out;

    DK dk;
    {
        float g1[25], g2[25], s1 = 0.f, s2 = 0.f;
        for (int i = 0; i < 5; i++)
            for (int j = 0; j < 5; j++) {
                float ai = (float)(i - 2), aj = (float)(j - 2);
                float r2 = ai*ai + aj*aj;
                g1[i*5+j] = expf(-r2/2.0f);
                g2[i*5+j] = expf(-r2/8.0f);
                s1 += g1[i*5+j]; s2 += g2[i*5+j];
            }
        for (int k = 0; k < 25; k++) dk.v[k] = g1[k]/s1 - g2[k]/s2;
    }

    hipMemcpyAsync(ws + OW1, w1, 1500*sizeof(float), hipMemcpyDeviceToDevice, stream);
    hipMemsetAsync(ws + OTQ1, 0, (OZEND - OTQ1)*sizeof(float), stream);
    hipMemsetAsync(ws + OZ3, 0, (size_t)B*30*LP*sizeof(float), stream);   // z3 must be zero (gated writes rely on it)
    hipMemsetAsync(ws + OPHI, 0, (OTOT2 - OPHI)*sizeof(float), stream);   // bf16 planes A + post planes
    hipMemsetAsync(ws + OZ4S, 0, (OZ4SEND - OZ4S)*sizeof(float), stream); // planes B + w2B + w1B + cnz4B + barrier
    k_prep<<<294, 256, 0, stream>>>(w2, ws + OW2P, (int*)(ws + OPZF),
                                    (int*)(ws + OSZF), (int*)(ws + OEAF));

    k_loop<<<256, 448, 0, stream>>>(x, b1, b2, ws, dk);

    k_fc1b<<<dim3(500, 4), 256, 0, stream>>>(ws + OG, fcw, fcb, ws + OHH);
    k_head_all<<<1, 640, 0, stream>>>(ws + OHH, outw, out);
}

// Round 4
// 1445.267 us; speedup vs baseline: 3.3873x; 3.3873x over previous
//
#include <hip/hip_runtime.h>
#include <math.h>

// ---------------- constants ----------------
#define DTMEM 0.1f   // DT*TAU_MEM_INV
#define DTSYN 0.2f   // DT*TAU_SYN_INV
#define DTTR  0.02f  // DT*TAU_PRE_INV == DT*TAU_POST_INV

static constexpr int B = 32, T = 32;
static constexpr int HD = 60, HP = 28;
static constexpr int LD = HD*HD, LP = HP*HP;

// lif0 state: slot-major [b][og:8][yh:2][i:7][tid:448] float2
static constexpr size_t SST = (size_t)B*8*2*7*448*2;      // 3,211,264 floats
// conv2 state: slot-major [b][jgg:7][slot:6][tid:384] float4
static constexpr size_t S2  = (size_t)B*7*6*384*4;        // 2,064,384 floats

// ---- workspace offsets (floats) ----
static constexpr size_t OW1A  = 0;                         // w1 ping (1500)
static constexpr size_t OW1B  = OW1A + 1500;               // w1 pong
static constexpr size_t OV0   = OW1B + 1500;               // zero-region start
static constexpr size_t OI0   = OV0 + SST;
static constexpr size_t OTQ1  = OI0 + SST;
static constexpr size_t OTP1A = OTQ1 + SST;                // [B,60,60]
static constexpr size_t OTP1B = OTP1A + (size_t)B*LD;
static constexpr size_t OTP2  = OTP1B + (size_t)B*LD;      // [B,30,28,28] master
static constexpr size_t OZ3A  = OTP2 + (size_t)B*30*LP;    // z3 ping
static constexpr size_t OZ3B  = OZ3A + (size_t)B*30*LP;    // z3 pong
static constexpr size_t OV1S  = OZ3B + (size_t)B*30*LP;
static constexpr size_t OI1S  = OV1S + S2;
static constexpr size_t OTQ2S = OI1S + S2;
static constexpr size_t OPHIA = OTQ2S + S2;                // u16 planes (376320 floats each)
static constexpr size_t OPLOA = OPHIA + 376320;
static constexpr size_t OPZ3A = OPLOA + 376320;
static constexpr size_t OPHIB = OPZ3A + 376320;
static constexpr size_t OPLOB = OPHIB + 376320;
static constexpr size_t OPZ3B = OPLOB + 376320;
static constexpr size_t OZEROEND = OPZ3B + 376320;         // zero-init [OV0, OZEROEND)
static constexpr size_t OEPA  = OZEROEND;                  // E partials [32][75000] f32
static constexpr size_t OEMA  = OEPA + (size_t)B*75000;
static constexpr size_t OEPB  = OEMA + (size_t)B*75000;
static constexpr size_t OEMB  = OEPB + (size_t)B*75000;
static constexpr size_t OPARTA = OEMB + (size_t)B*75000;   // part [30][50][64]
static constexpr size_t OPARTB = OPARTA + 96000;
static constexpr size_t OG    = OPARTB + 96000;            // [T][3200]
static constexpr size_t OHH   = OG + (size_t)T*3200;       // [T][500]
static constexpr size_t OW2A  = OHH + (size_t)T*500;       // w2 ping [100][30][28]
static constexpr size_t OW2B  = OW2A + 84000;
static constexpr size_t OCNZA = OW2B + 84000;              // int[960][4]
static constexpr size_t OCNZB = OCNZA + 3840;
static constexpr size_t OQZF  = OCNZB + 3840;              // int[512]
static constexpr size_t OPZF  = OQZF + 512;                // int[960]
static constexpr size_t OSZF  = OPZF + 960;                // int[224]
static constexpr size_t OEAA  = OSZF + 224;                // int[224] eact ping
static constexpr size_t OEAB  = OEAA + 224;                // int[224] eact pong
static constexpr size_t OEND  = OEAB + 224;

struct DK { float v[25]; };

typedef __attribute__((ext_vector_type(8))) short bfx8;
typedef __attribute__((ext_vector_type(4))) float f32x4;

static __device__ __forceinline__ unsigned short f2bf(float f) {
    unsigned u = __float_as_uint(f);
    return (unsigned short)((u + 0x7FFFu + ((u >> 16) & 1u)) >> 16);
}
static __device__ __forceinline__ float bf2f(unsigned short h) {
    return __uint_as_float(((unsigned)h) << 16);
}

// STDP w1 pair update (on/off channels share the same part sums).
static __device__ __forceinline__ float2 w1pair(const float* w1cur, const float* pprev,
                                                int o, int pp, int t) {
    float wa = w1cur[o*50 + pp], wb = w1cur[o*50 + 25 + pp];
    if (t > 0) {
        float EpS = 0.f, EmS = 0.f;
        for (int s = 0; s < 64; ++s) {
            EpS += pprev[((size_t)(o*50 + pp) << 6) + s];
            EmS += pprev[((size_t)(o*50 + 25 + pp) << 6) + s];
        }
        wa = fminf(fmaxf(wa + 0.004f*fmaxf(1.f-wa,0.f)*EpS - 0.003f*fmaxf(wa,0.f)*EmS, 0.f), 1.f);
        wb = fminf(fmaxf(wb + 0.004f*fmaxf(1.f-wb,0.f)*(-EpS) - 0.003f*fmaxf(wb,0.f)*(-EmS), 0.f), 1.f);
    }
    return make_float2(wa, wb);
}

// STDP w2 update for one element; e = (j*30+c)*25+p.
static __device__ __forceinline__ float w2eff(float w, int e, int jgg,
        const int* eaR, const float* EPr, const float* EMr) {
    float ep = 0.f, em = 0.f; int any = 0;
    for (int bb = 0; bb < 32; ++bb) {
        if (eaR[bb*7 + jgg]) {
            any = 1;
            ep += EPr[(size_t)bb*75000 + e];
            em += EMr[(size_t)bb*75000 + e];
        }
    }
    if (!any) return w;
    float dwp = 0.004f * fmaxf(1.0f - w, 0.0f) * ep;
    float dwm = 0.003f * fmaxf(w, 0.0f) * em;
    return fminf(fmaxf(w + dwp - dwm, 0.0f), 1.0f);
}

union SMEM {
    struct {
        float xsh[36*64];
        float zsh[32*60];
        float tsh[32*60];
        float red[700];
        float wd[100];
        int   sflags[8];
    } f;
    struct {
        union { float spre[LP]; unsigned short sB[10784]; } u;  // conv stage / corr B-planes(+zero blk)
        unsigned short aZ4[9216], aTH[9216], aTL[9216];         // corr A-planes [16][576]
        int sjany[16];
        int sany, sAnyTq, ganyJ;
        int sCA[30];
    } v;
};

// ================= one launch per timestep =================
// blocks 0..223:   conv2+LIF1+STDP-corr for step u = t-1 (per (b,jgg): 16 j-rows)
// blocks 224..735: front (DoG+tp1+conv1+LIF0+pool+part) for step t
__global__ __launch_bounds__(448) void k_step(
        const float* __restrict__ x, const float* __restrict__ b1,
        const float* __restrict__ b2, float* __restrict__ ws, DK dk, int t) {
    __shared__ __attribute__((aligned(16))) SMEM sm;
    const int blk = blockIdx.x, tid = threadIdx.x;

    if (blk < 224) {
        // ===================== conv2 + corr, step u = t-1 =====================
        const int u = t - 1;
        if (u < 0) return;
        const int cb = blk;
        const int jgg = cb % 7, b = cb / 7, jb0 = jgg*16;
        const float* w2cur = ws + ((u&1) ? OW2B : OW2A);
        float*       w2nxt = ws + ((u&1) ? OW2A : OW2B);
        const float* EPr = ws + ((u&1) ? OEPA : OEPB);   // E(u-1)
        const float* EMr = ws + ((u&1) ? OEMA : OEMB);
        float*       EPw = ws + ((u&1) ? OEPB : OEPA);   // E(u)
        float*       EMw = ws + ((u&1) ? OEMB : OEMA);
        const int*   eaR = (const int*)(ws + ((u&1) ? OEAA : OEAB));
        int*         eaW = (int*)(ws + ((u&1) ? OEAB : OEAA));
        const int*   cnzP = (const int*)(ws + ((u&1) ? OCNZB : OCNZA));
        const float* z3r = ws + ((u&1) ? OZ3B : OZ3A);
        const unsigned short* uhiR = (const unsigned short*)(ws + ((u&1) ? OPHIB : OPHIA));
        const unsigned short* uloR = (const unsigned short*)(ws + ((u&1) ? OPLOB : OPLOA));
        const unsigned short* uz3R = (const unsigned short*)(ws + ((u&1) ? OPZ3B : OPZ3A));
        int* szf = (int*)(ws + OSZF);
        float* g_t = ws + OG + (size_t)u*3200;

        // w2 persist (through u-1) — must run even on early-out
        if (u < 31) {
            int e = cb*448 + tid;
            if (e < 75000) {
                int j = e/750, r = e - j*750, c = r/25, p25 = r - c*25;
                size_t f = ((size_t)j*30 + c)*28 + p25;
                float w = w2cur[f];
                if (u >= 1) w = w2eff(w, e, j>>4, eaR, EPr, EMr);
                w2nxt[f] = w;
            }
        }

        if (tid == 0) { sm.v.sany = 0; sm.v.sAnyTq = 0; sm.v.ganyJ = 0; }
        if (tid < 16) sm.v.sjany[tid] = 0;
        __syncthreads();
        if (tid < 120 && cnzP[b*120 + tid]) atomicOr(&sm.v.sany, 1);
        if (tid < 30) {
            const int* cz = cnzP + (b*30 + tid)*4;
            sm.v.sCA[tid] = (cz[0] | cz[1] | cz[2] | cz[3]);
        }
        if (u >= 1 && tid < 32 && eaR[tid*7 + jgg]) atomicOr(&sm.v.ganyJ, 1);
        __syncthreads();
        const int szv = szf[b*7 + jgg];
        if (szv && !sm.v.sany) {
            // state provably zero, no input: everything stays zero
            if (tid < 16 && jb0 + tid < 100) g_t[b*100 + jb0 + tid] = 0.f;
            if (u < 31 && tid == 0) eaW[b*7 + jgg] = 0;
            return;
        }
        // ---- conv2 (384 threads: jp:8, xh:2, y:24) ----
        const bool run = tid < 384;
        int jp = tid & 7, xh = (tid >> 3) & 1, yv = tid >> 4;
        int j0 = jb0 + jp*2;
        int ja = (j0 < 100) ? j0 : 99, jbb = (j0+1 < 100) ? j0+1 : 99;
        int xx0 = xh*12;
        float acc0[12], acc1[12];
        #pragma unroll
        for (int xq = 0; xq < 12; xq++) { acc0[xq] = 0.f; acc1[xq] = 0.f; }
        const int gJ = sm.v.ganyJ;
        #pragma unroll 1
        for (int c = 0; c < 30; ++c) {
            bool act = sm.v.sCA[c] != 0;
            __syncthreads();
            if (act) {
                const float4* src = (const float4*)(z3r + (size_t)(b*30 + c)*LP);
                for (int i2 = tid; i2 < 196; i2 += 448) ((float4*)sm.v.u.spre)[i2] = src[i2];
            }
            __syncthreads();
            if (!act) continue;
            if (run) {
                float wa[28], wb[28];
                #pragma unroll
                for (int i = 0; i < 7; i++) {
                    ((float4*)wa)[i] = ((const float4*)(w2cur + ((size_t)ja*30 + c)*28))[i];
                    ((float4*)wb)[i] = ((const float4*)(w2cur + ((size_t)jbb*30 + c)*28))[i];
                }
                if (u >= 1 && gJ) {
                    #pragma unroll
                    for (int p25 = 0; p25 < 25; p25++) {
                        wa[p25] = w2eff(wa[p25], (ja*30 + c)*25 + p25, ja>>4, eaR, EPr, EMr);
                        wb[p25] = w2eff(wb[p25], (jbb*30 + c)*25 + p25, jbb>>4, eaR, EPr, EMr);
                    }
                }
                #pragma unroll
                for (int kh = 0; kh < 5; kh++) {
                    float rr[16];
                    const float4* r4 = (const float4*)&sm.v.u.spre[(yv+kh)*HP + xx0];
                    #pragma unroll
                    for (int i = 0; i < 4; i++) ((float4*)rr)[i] = r4[i];
                    #pragma unroll
                    for (int kw = 0; kw < 5; kw++) {
                        float w0 = wa[kh*5+kw], w1v = wb[kh*5+kw];
                        #pragma unroll
                        for (int xq = 0; xq < 12; xq++) {
                            acc0[xq] = fmaf(w0, rr[xq+kw], acc0[xq]);
                            acc1[xq] = fmaf(w1v, rr[xq+kw], acc1[xq]);
                        }
                    }
                }
            }
        }
        // ---- LIF1 + tq2 + LDS A-planes ----
        bool spk0 = false, spk1 = false, anyTq = false;
        if (run) {
            float4* v1p = (float4*)(ws + OV1S);
            float4* i1p = (float4*)(ws + OI1S);
            float4* t2p = (float4*)(ws + OTQ2S);
            size_t sb2 = ((size_t)(b*7 + jgg)*6)*384 + tid;
            #pragma unroll
            for (int jj = 0; jj < 2; jj++) {
                bool anyspk = false;
                int rj = jp*2 + jj;
                #pragma unroll
                for (int i = 0; i < 3; i++) {
                    size_t si = sb2 + (size_t)(jj*3 + i)*384;
                    float4 v4 = v1p[si];
                    float4 c4 = i1p[si];
                    float4 t4 = t2p[si];
                    float4 vn, in, zn4, tn4;
                    float* vp=(float*)&v4; float* cp=(float*)&c4; float* tp=(float*)&t4;
                    float* vnp=(float*)&vn; float* inp=(float*)&in;
                    float* znp=(float*)&zn4; float* tnp=(float*)&tn4;
                    #pragma unroll
                    for (int k = 0; k < 4; k++) {
                        float a = jj ? acc1[i*4+k] : acc0[i*4+k];
                        float vd = vp[k] + DTMEM*(cp[k] - vp[k]);
                        float z = (vd > 10.0f) ? 1.0f : 0.0f;
                        vnp[k] = (1.0f - z)*vd;
                        inp[k] = (cp[k] - DTSYN*cp[k]) + 10.0f*a;
                        znp[k] = z;
                        tnp[k] = tp[k] + DTTR*(z - tp[k]);
                        anyspk = anyspk || (z != 0.f);
                        anyTq = anyTq || (tnp[k] != 0.f);
                    }
                    v1p[si] = vn;
                    i1p[si] = in;
                    t2p[si] = tn4;
                    int col = yv*24 + xx0 + i*4;
                    ushort4 zb, hb, lb4;
                    unsigned short h;
                    zb.x = (znp[0]!=0.f)?(unsigned short)0x3F80:(unsigned short)0;
                    zb.y = (znp[1]!=0.f)?(unsigned short)0x3F80:(unsigned short)0;
                    zb.z = (znp[2]!=0.f)?(unsigned short)0x3F80:(unsigned short)0;
                    zb.w = (znp[3]!=0.f)?(unsigned short)0x3F80:(unsigned short)0;
                    h = f2bf(tnp[0]); hb.x = h; lb4.x = f2bf(tnp[0] - bf2f(h));
                    h = f2bf(tnp[1]); hb.y = h; lb4.y = f2bf(tnp[1] - bf2f(h));
                    h = f2bf(tnp[2]); hb.z = h; lb4.z = f2bf(tnp[2] - bf2f(h));
                    h = f2bf(tnp[3]); hb.w = h; lb4.w = f2bf(tnp[3] - bf2f(h));
                    *(ushort4*)&sm.v.aZ4[rj*576 + col] = zb;
                    *(ushort4*)&sm.v.aTH[rj*576 + col] = hb;
                    *(ushort4*)&sm.v.aTL[rj*576 + col] = lb4;
                }
                if (jj == 0) spk0 = anyspk; else spk1 = anyspk;
            }
            if (spk0 && j0 < 100) atomicOr(&sm.v.sjany[jp*2], 1);
            if (spk1 && j0+1 < 100) atomicOr(&sm.v.sjany[jp*2+1], 1);
            if (anyTq) atomicOr(&sm.v.sAnyTq, 1);
        }
        __syncthreads();
        if (tid < 16 && jb0 + tid < 100) g_t[b*100 + jb0 + tid] = sm.v.sjany[tid] ? 1.f : 0.f;
        if (tid == 0 && szv) szf[b*7 + jgg] = 0;
        // ---- STDP correlations for own 16 j rows (E(u) not needed at u==31) ----
        if (u < 31) {
            int m0i = 0;
            #pragma unroll
            for (int k = 0; k < 16; k++) m0i |= sm.v.sjany[k];
            bool m0 = (m0i != 0);
            bool mq = (sm.v.sAnyTq != 0);
            bool ea = m0 || mq;
            if (tid == 0) eaW[b*7 + jgg] = ea ? 1 : 0;
            if (!ea) return;
            for (int i2 = tid; i2 < 704; i2 += 448) sm.v.u.sB[10080 + i2] = 0;  // zero block
            int lane = tid & 63, wv = tid >> 6;
            int mode = wv >> 1, n = wv & 1;
            bool wact = (wv < 4);
            int p25 = n*16 + (lane & 15);
            int offB1, offB2;
            {
                int offH, offL, offZ;
                if (p25 < 25) {
                    int dy = p25/5, dx = p25 - dy*5;
                    offH = ((0*5 + dx)*672 + dy*24)*2;
                    offL = ((1*5 + dx)*672 + dy*24)*2;
                    offZ = ((2*5 + dx)*672 + dy*24)*2;
                } else { offH = offL = offZ = 10080*2; }
                offB1 = (mode == 0) ? offH : offZ;
                offB2 = (mode == 0) ? offL : offZ;
            }
            const unsigned short* A1 = (mode == 0) ? sm.v.aZ4 : sm.v.aTH;
            const unsigned short* A2 = (mode == 0) ? sm.v.aZ4 : sm.v.aTL;
            float* Ew = (mode == 0) ? EPw : EMw;
            int abase = (lane & 15)*576 + (lane >> 4)*8;
            const char* sBb = (const char*)sm.v.u.sB;
            #pragma unroll 1
            for (int c = 0; c < 30; ++c) {
                bool cAc = sm.v.sCA[c] != 0;
                __syncthreads();
                {   // stage B-planes for this c
                    const size_t pbase = (size_t)(b*30 + c)*784;
                    for (int idx = tid; idx < 784; idx += 448) {
                        int r = idx/28, col = idx - r*28;
                        #pragma unroll
                        for (int pl = 0; pl < 3; ++pl) {
                            bool need = (pl < 2) ? m0 : (cAc && mq);
                            if (!need) continue;
                            unsigned short vvv =
                                ((pl == 0) ? uhiR : (pl == 1) ? uloR : uz3R)[pbase + idx];
                            int base = pl*5*672 + r*24;
                            #pragma unroll
                            for (int dx = 0; dx < 5; ++dx) {
                                int xx = col - dx;
                                if (xx >= 0 && xx < 24) sm.v.u.sB[base + dx*672 + xx] = vvv;
                            }
                        }
                    }
                }
                __syncthreads();
                if (!wact) continue;
                f32x4 C = (f32x4){0.f, 0.f, 0.f, 0.f};
                bool go = (mode == 0) ? m0 : (mq && cAc);
                if (go) {
                    for (int ks = 0; ks < 18; ++ks) {
                        int kk = ks*32 + (lane >> 4)*8;
                        bfx8 a1 = *(const bfx8*)(A1 + abase + ks*32);
                        bfx8 a2 = *(const bfx8*)(A2 + abase + ks*32);
                        bfx8 b1v = *(const bfx8*)(sBb + offB1 + kk*2);
                        bfx8 b2v = *(const bfx8*)(sBb + offB2 + kk*2);
                        C = __builtin_amdgcn_mfma_f32_16x16x32_bf16(a1, b1v, C, 0, 0, 0);
                        C = __builtin_amdgcn_mfma_f32_16x16x32_bf16(a2, b2v, C, 0, 0, 0);
                    }
                }
                if (p25 < 25) {
                    #pragma unroll
                    for (int q = 0; q < 4; ++q) {
                        int j = jb0 + (lane >> 4)*4 + q;
                        if (j < 100)
                            Ew[(size_t)b*75000 + ((size_t)j*30 + c)*25 + p25] = C[q];
                    }
                }
            }
        }
        return;
    }

    // ===================== front, step t =====================
    if (t >= T) return;
    const int fb = blk - 224;
    const int og = fb & 7, by = fb >> 3;
    const int b = by >> 1, yh = by & 1, y0 = yh*28;

    const float* tp1r = ws + ((t&1) ? OTP1B : OTP1A);
    float*       tp1w = ws + ((t&1) ? OTP1A : OTP1B);
    const float* w1cur = ws + ((t&1) ? OW1B : OW1A);
    float*       w1nxt = ws + ((t&1) ? OW1A : OW1B);
    float*       partW = ws + ((t&1) ? OPARTB : OPARTA);
    const float* pprev = ws + ((t&1) ? OPARTA : OPARTB);
    int*         cnzW  = (int*)(ws + ((t&1) ? OCNZB : OCNZA));
    float*       z3W   = ws + ((t&1) ? OZ3B : OZ3A);
    unsigned short* uhiW = (unsigned short*)(ws + ((t&1) ? OPHIB : OPHIA));
    unsigned short* uloW = (unsigned short*)(ws + ((t&1) ? OPLOB : OPLOA));
    unsigned short* uz3W = (unsigned short*)(ws + ((t&1) ? OPZ3B : OPZ3A));
    float* v0g = ws + OV0; float* i0g = ws + OI0; float* tq1g = ws + OTQ1;
    float* tp2g = ws + OTP2;
    int* qzf = (int*)(ws + OQZF);
    int* pzf = (int*)(ws + OPZF);

    int qzOld = qzf[(b*8 + og)*2 + yh];
    {
        const float4* xs = (const float4*)(x + ((size_t)t*B + b)*4096) + y0*16;
        const float4* ts = (const float4*)(tp1r + (size_t)b*LD) + y0*15;
        for (int i2 = tid; i2 < 576; i2 += 448) ((float4*)sm.f.xsh)[i2] = xs[i2];
        for (int i2 = tid; i2 < 480; i2 += 448) ((float4*)sm.f.tsh)[i2] = ts[i2];
    }
    if (tid < 100) {
        int oo2 = tid / 25, pp = tid % 25;
        int o2 = og*4 + oo2; if (o2 > 29) o2 = 29;
        float2 wp = w1pair(w1cur, pprev, o2, pp, t);
        sm.f.wd[tid] = wp.x - wp.y;
    }
    if (fb < 4) {
        int e = fb*448 + tid;
        if (e < 1500) {
            int o = e/50, r = e%50, ch = r/25, pp = r%25;
            float2 wp = w1pair(w1cur, pprev, o, pp, t);
            w1nxt[e] = ch ? wp.y : wp.x;
        }
    }
    if (tid < 8) sm.f.sflags[tid] = 0;
    __syncthreads();
    float bias = b1[0] - b2[0];
    // DoG + tp1 trace (og==0 persists tp1)
    for (int idx = tid; idx < 1920; idx += 448) {
        int lr = idx / 60, c = idx % 60;
        float a = 0.f;
        #pragma unroll
        for (int kh = 0; kh < 5; kh++)
            #pragma unroll
            for (int kw = 0; kw < 5; kw++)
                a = fmaf(dk.v[kh*5+kw], sm.f.xsh[(lr+kh)*64 + c + kw], a);
        float zv = a + bias;
        sm.f.zsh[idx] = zv;
        float tp = sm.f.tsh[idx];
        tp = tp + DTTR*(zv - tp);
        sm.f.tsh[idx] = tp;
        if (og == 0) tp1w[(size_t)b*LD + (y0 + lr)*60 + c] = tp;
    }
    __syncthreads();
    int oo = tid & 3, xq = (tid >> 2) & 3, yv = tid >> 4;
    int o = og*4 + oo, xx0 = xq*14;
    bool valid = (o < 30);
    float zn[14], tn[14];
    float zs = 0.f, qs = 0.f;
    bool anym = false;
    if (valid) {
        float acc[14];
        #pragma unroll
        for (int k = 0; k < 14; k++) acc[k] = 0.f;
        #pragma unroll
        for (int kh = 0; kh < 5; kh++) {
            float rr[18];
            const float2* r2 = (const float2*)&sm.f.zsh[(yv+kh)*HD + xx0];
            #pragma unroll
            for (int i = 0; i < 9; i++) ((float2*)rr)[i] = r2[i];
            #pragma unroll
            for (int kw = 0; kw < 5; kw++) {
                float w = sm.f.wd[oo*25 + kh*5 + kw];
                #pragma unroll
                for (int k = 0; k < 14; k++) acc[k] = fmaf(w, rr[k+kw], acc[k]);
            }
        }
        // LIF0 + tq1 (slot-major float2, sticky-zero gated tq1)
        float2* v0p = (float2*)v0g;
        float2* i0p = (float2*)i0g;
        float2* tq1p = (float2*)tq1g;
        size_t sb = ((size_t)((b*8 + og)*2 + yh)*7)*448 + tid;
        #pragma unroll
        for (int i = 0; i < 7; i++) {
            float2 v2 = v0p[sb + (size_t)i*448];
            float2 c2 = i0p[sb + (size_t)i*448];
            float2 t2;
            if (qzOld) { t2.x = 0.f; t2.y = 0.f; }
            else t2 = tq1p[sb + (size_t)i*448];
            float2 vn, in, tn2;
            bool sp = false;
            #pragma unroll
            for (int k = 0; k < 2; k++) {
                int e = i*2 + k;
                float vv = k ? v2.y : v2.x, cc = k ? c2.y : c2.x, tt = k ? t2.y : t2.x;
                float vd = vv + DTMEM*(cc - vv);
                float z = (vd > 15.0f) ? 1.0f : 0.0f;
                float vo = (1.0f - z)*vd;
                float io_ = (cc - DTSYN*cc) + acc[e];
                float tq = tt + DTTR*(z - tt);
                if (k) { vn.y = vo; in.y = io_; tn2.y = tq; } else { vn.x = vo; in.x = io_; tn2.x = tq; }
                zn[e] = z; tn[e] = tq;
                sp = sp || (z != 0.f);
            }
            v0p[sb + (size_t)i*448] = vn;
            i0p[sb + (size_t)i*448] = in;
            if (!qzOld || sp) tq1p[sb + (size_t)i*448] = tn2;
        }
        #pragma unroll
        for (int k = 0; k < 14; k++) { zs += zn[k]; qs += tn[k]; }
        float mx[7];
        #pragma unroll
        for (int k = 0; k < 7; k++) mx[k] = fmaxf(zn[2*k], zn[2*k+1]);
        #pragma unroll
        for (int k = 0; k < 7; k++) {
            float pm = __shfl_xor(mx[k], 16, 64);   // y-partner (y^1)
            mx[k] = fmaxf(mx[k], pm);
        }
        if ((yv & 1) == 0) {
            int pzOld = pzf[b*30 + o];
            int py = yh*14 + (yv >> 1);
            size_t pb = ((size_t)(b*30 + o)*HP + py)*HP + xq*7;
            #pragma unroll
            for (int k = 0; k < 7; k++) {
                float m = mx[k];
                anym = anym || (m != 0.f);
                if (!pzOld || m != 0.f) {
                    z3W[pb + k] = m;
                    float tpv = pzOld ? 0.f : tp2g[pb + k];
                    float tnew = tpv + DTTR*(m - tpv);
                    tp2g[pb + k] = tnew;
                    unsigned short h = f2bf(tnew);
                    uhiW[pb + k] = h;
                    uloW[pb + k] = f2bf(tnew - bf2f(h));
                    uz3W[pb + k] = (m != 0.f) ? (unsigned short)0x3F80 : (unsigned short)0;
                }
            }
        }
    }
    if (anym) atomicOr(&sm.f.sflags[oo*2 + (xq >> 1)], 1);
    int lane = tid & 63, wave = tid >> 6;
    // pass 1: minus correlation (unfold(z0) x tq1_new)
    {
        float a[25];
        #pragma unroll
        for (int pq = 0; pq < 25; pq++) a[pq] = 0.f;
        if (valid && qs != 0.f) {
            #pragma unroll
            for (int kh = 0; kh < 5; kh++) {
                float rr[18];
                const float2* r2 = (const float2*)&sm.f.zsh[(yv+kh)*HD + xx0];
                #pragma unroll
                for (int i = 0; i < 9; i++) ((float2*)rr)[i] = r2[i];
                #pragma unroll
                for (int kw = 0; kw < 5; kw++)
                    #pragma unroll
                    for (int k = 0; k < 14; k++)
                        a[kh*5+kw] = fmaf(rr[k+kw], tn[k], a[kh*5+kw]);
            }
        }
        #pragma unroll
        for (int q = 0; q < 25; q++) {
            float v = a[q];
            v += __shfl_xor(v, 4, 64);
            v += __shfl_xor(v, 8, 64);
            v += __shfl_xor(v, 16, 64);
            v += __shfl_xor(v, 32, 64);
            if (lane < 4) sm.f.red[wave*100 + lane*25 + q] = v;
        }
    }
    __syncthreads();
    int anyblk = sm.f.sflags[0]|sm.f.sflags[1]|sm.f.sflags[2]|sm.f.sflags[3]|
                 sm.f.sflags[4]|sm.f.sflags[5]|sm.f.sflags[6]|sm.f.sflags[7];
    if (tid < 100) {
        int oo2 = tid / 25, q = tid % 25;
        float s = 0.f;
        #pragma unroll
        for (int w = 0; w < 7; w++) s += sm.f.red[w*100 + oo2*25 + q];
        int o2 = og*4 + oo2;
        if (o2 < 30) partW[((size_t)(o2*50 + 25 + q) << 6) + b*2 + yh] = s;
    }
    if (tid < 8) {
        int o2 = og*4 + (tid >> 1);
        if (o2 < 30) cnzW[(b*30 + o2)*4 + yh*2 + (tid & 1)] = sm.f.sflags[tid];
    }
    if (tid < 4) {  // sticky plane-zero clear (benign cross-yh race: both write 0)
        int o2 = og*4 + tid;
        if (o2 < 30 && (sm.f.sflags[tid*2] | sm.f.sflags[tid*2+1])) pzf[b*30 + o2] = 0;
    }
    if (tid == 0 && qzOld && anyblk) qzf[(b*8 + og)*2 + yh] = 0;
    __syncthreads();
    // pass 2: plus correlation (unfold(tp1_new) x z2)
    {
        float a[25];
        #pragma unroll
        for (int pq = 0; pq < 25; pq++) a[pq] = 0.f;
        if (valid && zs != 0.f) {
            #pragma unroll
            for (int kh = 0; kh < 5; kh++) {
                float rr[18];
                const float2* r2 = (const float2*)&sm.f.tsh[(yv+kh)*HD + xx0];
                #pragma unroll
                for (int i = 0; i < 9; i++) ((float2*)rr)[i] = r2[i];
                #pragma unroll
                for (int kw = 0; kw < 5; kw++)
                    #pragma unroll
                    for (int k = 0; k < 14; k++)
                        a[kh*5+kw] = fmaf(rr[k+kw], zn[k], a[kh*5+kw]);
            }
        }
        #pragma unroll
        for (int q = 0; q < 25; q++) {
            float v = a[q];
            v += __shfl_xor(v, 4, 64);
            v += __shfl_xor(v, 8, 64);
            v += __shfl_xor(v, 16, 64);
            v += __shfl_xor(v, 32, 64);
            if (lane < 4) sm.f.red[wave*100 + lane*25 + q] = v;
        }
    }
    __syncthreads();
    if (tid < 100) {
        int oo2 = tid / 25, q = tid % 25;
        float s = 0.f;
        #pragma unroll
        for (int w = 0; w < 7; w++) s += sm.f.red[w*100 + oo2*25 + q];
        int o2 = og*4 + oo2;
        if (o2 < 30) partW[((size_t)(o2*50 + q) << 6) + b*2 + yh] = s;
    }
}

// ================= k_prep: padded w2 + flag init =================
__global__ void k_prep(const float* __restrict__ w2, float* __restrict__ w2p,
                       int* __restrict__ qzf, int* __restrict__ pzf,
                       int* __restrict__ szf) {
    int e = blockIdx.x*blockDim.x + threadIdx.x;
    if (e < 75000) {
        int j = e / 750, r = e % 750, c = r / 25, p = r % 25;
        w2p[((size_t)j*30 + c)*28 + p] = w2[e];
    }
    if (e < 512) qzf[e] = 1;
    if (e < 960) pzf[e] = 1;
    if (e < 224) szf[e] = 1;
}

// ================= k_fc1b: batched fc1, grid (500 n, 4 t-quarters) =================
__global__ __launch_bounds__(256) void k_fc1b(
        const float* __restrict__ g_all, const float* __restrict__ fcw,
        const float* __restrict__ fcb, float* __restrict__ h_all) {
    __shared__ float red[8][4];
    int n = blockIdx.x, by = blockIdx.y, tid = threadIdx.x;
    const float4* w4 = (const float4*)(fcw + (size_t)n*3200);
    float4 wreg[4];
    #pragma unroll
    for (int i = 0; i < 4; i++) {
        int k = tid + 256*i;
        if (k < 800) wreg[i] = w4[k];
    }
    float accs[8];
    #pragma unroll
    for (int tt = 0; tt < 8; tt++) accs[tt] = 0.f;
    #pragma unroll 1
    for (int tt = 0; tt < 8; tt++) {
        int t = by*8 + tt;
        const float4* g4 = (const float4*)(g_all + (size_t)t*3200);
        float a = 0.f;
        #pragma unroll
        for (int i = 0; i < 4; i++) {
            int k = tid + 256*i;
            if (k < 800) {
                float4 gv = g4[k];
                a = fmaf(gv.x, wreg[i].x, a);
                a = fmaf(gv.y, wreg[i].y, a);
                a = fmaf(gv.z, wreg[i].z, a);
                a = fmaf(gv.w, wreg[i].w, a);
            }
        }
        accs[tt] = a;
    }
    int lane = tid & 63, wid = tid >> 6;
    #pragma unroll
    for (int tt = 0; tt < 8; tt++) {
        float v = accs[tt];
        #pragma unroll
        for (int s = 32; s >= 1; s >>= 1) v += __shfl_down(v, s, 64);
        if (lane == 0) red[tt][wid] = v;
    }
    __syncthreads();
    if (tid < 8)
        h_all[(size_t)(by*8 + tid)*500 + n] =
            red[tid][0] + red[tid][1] + red[tid][2] + red[tid][3] + fcb[n];
}

// ================= k_head_all: LIF2 + LI readout =================
__global__ __launch_bounds__(640) void k_head_all(
        const float* __restrict__ h_all, const float* __restrict__ outw,
        float* __restrict__ out) {
    __shared__ float spk[500];
    __shared__ float vout[10];
    int tid = threadIdx.x;
    int wid = tid >> 6, lane = tid & 63;
    float v2r = 0.f, i2r = 0.f;
    float vor = 0.f, ior = 0.f;
    #pragma unroll 1
    for (int t = 0; t < 32; t++) {
        if (tid < 500) {
            float cur = i2r;
            float vd = v2r + DTMEM*(cur - v2r);
            float z = (vd > 1.0f) ? 1.0f : 0.0f;
            v2r = (1.0f - z)*vd;
            i2r = (cur - DTSYN*cur) + h_all[t*500 + tid];
            spk[tid] = z;
        }
        __syncthreads();
        float acc = 0.f;
        for (int n = lane; n < 500; n += 64)
            acc = fmaf(spk[n], outw[wid*500 + n], acc);
        #pragma unroll
        for (int s = 32; s >= 1; s >>= 1) acc += __shfl_down(acc, s, 64);
        if (lane == 0) {
            float ij = ior + acc;
            float vn = vor + DTMEM*(ij - vor);
            ior = ij - DTSYN*ij;
            vor = vn;
            vout[wid] = vn;
        }
        __syncthreads();
        if (tid < 320) out[(size_t)t*320 + tid] = vout[tid % 10];
        __syncthreads();
    }
}

// ---------------- launcher ----------------
extern "C" void kernel_launch(void* const* d_in, const int* in_sizes, int n_in,
                              void* d_out, int out_size, void* d_ws, size_t ws_size,
                              hipStream_t stream) {
    const float* x    = (const float*)d_in[0];
    const float* b1   = (const float*)d_in[1];
    const float* b2   = (const float*)d_in[2];
    const float* w1   = (const float*)d_in[3];
    const float* w2   = (const float*)d_in[4];
    const float* fcw  = (const float*)d_in[5];
    const float* fcb  = (const float*)d_in[6];
    const float* outw = (const float*)d_in[7];
    float* ws  = (float*)d_ws;
    float* out = (float*)d_out;

    DK dk;
    {
        float g1[25], g2[25], s1 = 0.f, s2 = 0.f;
        for (int i = 0; i < 5; i++)
            for (int j = 0; j < 5; j++) {
                float ai = (float)(i - 2), aj = (float)(j - 2);
                float r2 = ai*ai + aj*aj;
                g1[i*5+j] = expf(-r2/2.0f);
                g2[i*5+j] = expf(-r2/8.0f);
                s1 += g1[i*5+j]; s2 += g2[i*5+j];
            }
        for (int k = 0; k < 25; k++) dk.v[k] = g1[k]/s1 - g2[k]/s2;
    }

    hipMemcpyAsync(ws + OW1A, w1, 1500*sizeof(float), hipMemcpyDeviceToDevice, stream);
    hipMemsetAsync(ws + OV0, 0, (OZEROEND - OV0)*sizeof(float), stream);
    k_prep<<<294, 256, 0, stream>>>(w2, ws + OW2A, (int*)(ws + OQZF),
                                    (int*)(ws + OPZF), (int*)(ws + OSZF));

    for (int t = 0; t <= T; ++t)
        k_step<<<736, 448, 0, stream>>>(x, b1, b2, ws, dk, t);

    k_fc1b<<<dim3(500, 4), 256, 0, stream>>>(ws + OG, fcw, fcb, ws + OHH);
    k_head_all<<<1, 640, 0, stream>>>(ws + OHH, outw, out);
}

// Round 5
// 1016.158 us; speedup vs baseline: 4.8177x; 1.4223x over previous
//
#include <hip/hip_runtime.h>
#include <math.h>

// ---------------- constants ----------------
#define DTMEM 0.1f   // DT*TAU_MEM_INV
#define DTSYN 0.2f   // DT*TAU_SYN_INV
#define DTTR  0.02f  // DT*TAU_PRE_INV == DT*TAU_POST_INV

static constexpr int B = 32, T = 32;
static constexpr int HD = 60, HP = 28;
static constexpr int LD = HD*HD, LP = HP*HP;

// lif0 state: slot-major [b][og:8][yh:2][i:7][tid:448] float4 (v0.x,v0.y,i0.x,i0.y)
static constexpr size_t SVI = (size_t)B*8*2*7*448*4;      // 6,422,528 floats
// tq1: slot-major [b][og:8][yh:2][i:7][tid:448] float2
static constexpr size_t SST = (size_t)B*8*2*7*448*2;      // 3,211,264 floats
// conv2 state: slot-major [b][jgg:7][slot:6][tid:384] float4
static constexpr size_t S2  = (size_t)B*7*6*384*4;        // 2,064,384 floats

// ---- workspace offsets (floats) ----
static constexpr size_t OW1A  = 0;                         // w1 ping (1500)
static constexpr size_t OW1B  = OW1A + 1500;               // w1 pong
static constexpr size_t OVI0  = OW1B + 1500;               // zero-region start
static constexpr size_t OTQ1  = OVI0 + SVI;
static constexpr size_t OTP1A = OTQ1 + SST;                // [B,60,60]
static constexpr size_t OTP1B = OTP1A + (size_t)B*LD;
static constexpr size_t OTP2  = OTP1B + (size_t)B*LD;      // [B,30,28,28] master
static constexpr size_t OZ3A  = OTP2 + (size_t)B*30*LP;    // z3 ping
static constexpr size_t OZ3B  = OZ3A + (size_t)B*30*LP;    // z3 pong
static constexpr size_t OV1S  = OZ3B + (size_t)B*30*LP;
static constexpr size_t OI1S  = OV1S + S2;
static constexpr size_t OTQ2S = OI1S + S2;
static constexpr size_t OPHIA = OTQ2S + S2;                // u16 planes (376320 floats each)
static constexpr size_t OPLOA = OPHIA + 376320;
static constexpr size_t OPZ3A = OPLOA + 376320;
static constexpr size_t OPHIB = OPZ3A + 376320;
static constexpr size_t OPLOB = OPHIB + 376320;
static constexpr size_t OPZ3B = OPLOB + 376320;
static constexpr size_t OZEROEND = OPZ3B + 376320;         // zero-init [OVI0, OZEROEND)
static constexpr size_t OEPA  = OZEROEND;                  // E partials [32][75000] f32
static constexpr size_t OEMA  = OEPA + (size_t)B*75000;
static constexpr size_t OEPB  = OEMA + (size_t)B*75000;
static constexpr size_t OEMB  = OEPB + (size_t)B*75000;
static constexpr size_t OPARTA = OEMB + (size_t)B*75000;   // part [64 slots][1500] (slot-major!)
static constexpr size_t OPARTB = OPARTA + 96000;
static constexpr size_t OG    = OPARTB + 96000;            // [T][3200]
static constexpr size_t OHH   = OG + (size_t)T*3200;       // [T][500]
static constexpr size_t OW2A  = OHH + (size_t)T*500;       // w2 ping [100][30][28]
static constexpr size_t OW2B  = OW2A + 84000;
static constexpr size_t OCNZA = OW2B + 84000;              // int[960][4]
static constexpr size_t OCNZB = OCNZA + 3840;
static constexpr size_t OQZF  = OCNZB + 3840;              // int[512]
static constexpr size_t OPZF  = OQZF + 512;                // int[960]
static constexpr size_t OSZF  = OPZF + 960;                // int[224]
static constexpr size_t OEAA  = OSZF + 224;                // int[224] eact ping
static constexpr size_t OEAB  = OEAA + 224;                // int[224] eact pong
static constexpr size_t OEND  = OEAB + 224;

struct DK { float v[25]; };

typedef __attribute__((ext_vector_type(8))) short bfx8;
typedef __attribute__((ext_vector_type(4))) float f32x4;

static __device__ __forceinline__ unsigned short f2bf(float f) {
    unsigned u = __float_as_uint(f);
    return (unsigned short)((u + 0x7FFFu + ((u >> 16) & 1u)) >> 16);
}
static __device__ __forceinline__ float bf2f(unsigned short h) {
    return __uint_as_float(((unsigned)h) << 16);
}

// STDP w1 pair update; part is slot-major [s:64][1500] -> coalesced row reads.
static __device__ __forceinline__ float2 w1pair(const float* w1cur, const float* pprev,
                                                int o, int pp, int t) {
    float wa = w1cur[o*50 + pp], wb = w1cur[o*50 + 25 + pp];
    if (t > 0) {
        float EpS = 0.f, EmS = 0.f;
        for (int s = 0; s < 64; ++s) {
            EpS += pprev[s*1500 + o*50 + pp];
            EmS += pprev[s*1500 + o*50 + 25 + pp];
        }
        wa = fminf(fmaxf(wa + 0.004f*fmaxf(1.f-wa,0.f)*EpS - 0.003f*fmaxf(wa,0.f)*EmS, 0.f), 1.f);
        wb = fminf(fmaxf(wb + 0.004f*fmaxf(1.f-wb,0.f)*(-EpS) - 0.003f*fmaxf(wb,0.f)*(-EmS), 0.f), 1.f);
    }
    return make_float2(wa, wb);
}

// STDP w2 update for one element; e = (j*30+c)*25+p.
static __device__ __forceinline__ float w2eff(float w, int e, int jgg,
        const int* eaR, const float* EPr, const float* EMr) {
    float ep = 0.f, em = 0.f; int any = 0;
    for (int bb = 0; bb < 32; ++bb) {
        if (eaR[bb*7 + jgg]) {
            any = 1;
            ep += EPr[(size_t)bb*75000 + e];
            em += EMr[(size_t)bb*75000 + e];
        }
    }
    if (!any) return w;
    float dwp = 0.004f * fmaxf(1.0f - w, 0.0f) * ep;
    float dwm = 0.003f * fmaxf(w, 0.0f) * em;
    return fminf(fmaxf(w + dwp - dwm, 0.0f), 1.0f);
}

union SMEM {
    struct {
        float xsh[36*64];
        float zsh[32*60];
        float tsh[32*60];
        float red[700];
        float wd[100];
        int   sflags[8];
    } f;
    struct {
        union { float spre[LP]; unsigned short sB[10784]; } u;  // conv stage / corr B-planes(+zero blk)
        unsigned short aZ4[9216], aTH[9216], aTL[9216];         // corr A-planes [16][576]
        int sjany[16];
        int sany, sAnyTq, ganyJ;
        int sCA[30];
    } v;
};

// ================= one launch per timestep =================
// blocks 0..223:   conv2+LIF1+STDP-corr for step u = t-1 (per (b,jgg): 16 j-rows)
// blocks 224..735: front (DoG+tp1+conv1+LIF0+pool+part) for step t
__global__ __launch_bounds__(448) void k_step(
        const float* __restrict__ x, const float* __restrict__ b1,
        const float* __restrict__ b2, float* __restrict__ ws, DK dk, int t) {
    __shared__ __attribute__((aligned(16))) SMEM sm;
    const int blk = blockIdx.x, tid = threadIdx.x;

    if (blk < 224) {
        // ===================== conv2 + corr, step u = t-1 =====================
        const int u = t - 1;
        if (u < 0) return;
        const int cb = blk;
        const int jgg = cb % 7, b = cb / 7, jb0 = jgg*16;
        const float* w2cur = ws + ((u&1) ? OW2B : OW2A);
        float*       w2nxt = ws + ((u&1) ? OW2A : OW2B);
        const float* EPr = ws + ((u&1) ? OEPA : OEPB);   // E(u-1)
        const float* EMr = ws + ((u&1) ? OEMA : OEMB);
        float*       EPw = ws + ((u&1) ? OEPB : OEPA);   // E(u)
        float*       EMw = ws + ((u&1) ? OEMB : OEMA);
        const int*   eaR = (const int*)(ws + ((u&1) ? OEAA : OEAB));
        int*         eaW = (int*)(ws + ((u&1) ? OEAB : OEAA));
        const int*   cnzP = (const int*)(ws + ((u&1) ? OCNZB : OCNZA));
        const float* z3r = ws + ((u&1) ? OZ3B : OZ3A);
        const unsigned short* uhiR = (const unsigned short*)(ws + ((u&1) ? OPHIB : OPHIA));
        const unsigned short* uloR = (const unsigned short*)(ws + ((u&1) ? OPLOB : OPLOA));
        const unsigned short* uz3R = (const unsigned short*)(ws + ((u&1) ? OPZ3B : OPZ3A));
        int* szf = (int*)(ws + OSZF);
        float* g_t = ws + OG + (size_t)u*3200;

        // w2 persist (through u-1) — must run even on early-out
        if (u < 31) {
            int e = cb*448 + tid;
            if (e < 75000) {
                int j = e/750, r = e - j*750, c = r/25, p25 = r - c*25;
                size_t f = ((size_t)j*30 + c)*28 + p25;
                float w = w2cur[f];
                if (u >= 1) w = w2eff(w, e, j>>4, eaR, EPr, EMr);
                w2nxt[f] = w;
            }
        }

        if (tid == 0) { sm.v.sany = 0; sm.v.sAnyTq = 0; sm.v.ganyJ = 0; }
        if (tid < 16) sm.v.sjany[tid] = 0;
        __syncthreads();
        if (tid < 120 && cnzP[b*120 + tid]) atomicOr(&sm.v.sany, 1);
        if (tid < 30) {
            const int* cz = cnzP + (b*30 + tid)*4;
            sm.v.sCA[tid] = (cz[0] | cz[1] | cz[2] | cz[3]);
        }
        if (u >= 1 && tid < 32 && eaR[tid*7 + jgg]) atomicOr(&sm.v.ganyJ, 1);
        __syncthreads();
        const int szv = szf[b*7 + jgg];
        if (szv && !sm.v.sany) {
            // state provably zero, no input: everything stays zero
            if (tid < 16 && jb0 + tid < 100) g_t[b*100 + jb0 + tid] = 0.f;
            if (u < 31 && tid == 0) eaW[b*7 + jgg] = 0;
            return;
        }
        // ---- conv2 (384 threads: jp:8, xh:2, y:24) ----
        const bool run = tid < 384;
        int jp = tid & 7, xh = (tid >> 3) & 1, yv = tid >> 4;
        int j0 = jb0 + jp*2;
        int ja = (j0 < 100) ? j0 : 99, jbb = (j0+1 < 100) ? j0+1 : 99;
        int xx0 = xh*12;
        float acc0[12], acc1[12];
        #pragma unroll
        for (int xq = 0; xq < 12; xq++) { acc0[xq] = 0.f; acc1[xq] = 0.f; }
        const int gJ = sm.v.ganyJ;
        #pragma unroll 1
        for (int c = 0; c < 30; ++c) {
            bool act = sm.v.sCA[c] != 0;
            __syncthreads();
            if (act) {
                const float4* src = (const float4*)(z3r + (size_t)(b*30 + c)*LP);
                for (int i2 = tid; i2 < 196; i2 += 448) ((float4*)sm.v.u.spre)[i2] = src[i2];
            }
            __syncthreads();
            if (!act) continue;
            if (run) {
                float wa[28], wb[28];
                #pragma unroll
                for (int i = 0; i < 7; i++) {
                    ((float4*)wa)[i] = ((const float4*)(w2cur + ((size_t)ja*30 + c)*28))[i];
                    ((float4*)wb)[i] = ((const float4*)(w2cur + ((size_t)jbb*30 + c)*28))[i];
                }
                if (u >= 1 && gJ) {
                    #pragma unroll
                    for (int p25 = 0; p25 < 25; p25++) {
                        wa[p25] = w2eff(wa[p25], (ja*30 + c)*25 + p25, ja>>4, eaR, EPr, EMr);
                        wb[p25] = w2eff(wb[p25], (jbb*30 + c)*25 + p25, jbb>>4, eaR, EPr, EMr);
                    }
                }
                #pragma unroll
                for (int kh = 0; kh < 5; kh++) {
                    float rr[16];
                    const float4* r4 = (const float4*)&sm.v.u.spre[(yv+kh)*HP + xx0];
                    #pragma unroll
                    for (int i = 0; i < 4; i++) ((float4*)rr)[i] = r4[i];
                    #pragma unroll
                    for (int kw = 0; kw < 5; kw++) {
                        float w0 = wa[kh*5+kw], w1v = wb[kh*5+kw];
                        #pragma unroll
                        for (int xq = 0; xq < 12; xq++) {
                            acc0[xq] = fmaf(w0, rr[xq+kw], acc0[xq]);
                            acc1[xq] = fmaf(w1v, rr[xq+kw], acc1[xq]);
                        }
                    }
                }
            }
        }
        // ---- LIF1 + tq2 + LDS A-planes ----
        bool spk0 = false, spk1 = false, anyTq = false;
        if (run) {
            float4* v1p = (float4*)(ws + OV1S);
            float4* i1p = (float4*)(ws + OI1S);
            float4* t2p = (float4*)(ws + OTQ2S);
            size_t sb2 = ((size_t)(b*7 + jgg)*6)*384 + tid;
            #pragma unroll
            for (int jj = 0; jj < 2; jj++) {
                bool anyspk = false;
                int rj = jp*2 + jj;
                #pragma unroll
                for (int i = 0; i < 3; i++) {
                    size_t si = sb2 + (size_t)(jj*3 + i)*384;
                    float4 v4 = v1p[si];
                    float4 c4 = i1p[si];
                    float4 t4 = t2p[si];
                    float4 vn, in, zn4, tn4;
                    float* vp=(float*)&v4; float* cp=(float*)&c4; float* tp=(float*)&t4;
                    float* vnp=(float*)&vn; float* inp=(float*)&in;
                    float* znp=(float*)&zn4; float* tnp=(float*)&tn4;
                    #pragma unroll
                    for (int k = 0; k < 4; k++) {
                        float a = jj ? acc1[i*4+k] : acc0[i*4+k];
                        float vd = vp[k] + DTMEM*(cp[k] - vp[k]);
                        float z = (vd > 10.0f) ? 1.0f : 0.0f;
                        vnp[k] = (1.0f - z)*vd;
                        inp[k] = (cp[k] - DTSYN*cp[k]) + 10.0f*a;
                        znp[k] = z;
                        tnp[k] = tp[k] + DTTR*(z - tp[k]);
                        anyspk = anyspk || (z != 0.f);
                        anyTq = anyTq || (tnp[k] != 0.f);
                    }
                    v1p[si] = vn;
                    i1p[si] = in;
                    t2p[si] = tn4;
                    int col = yv*24 + xx0 + i*4;
                    ushort4 zb, hb, lb4;
                    unsigned short h;
                    zb.x = (znp[0]!=0.f)?(unsigned short)0x3F80:(unsigned short)0;
                    zb.y = (znp[1]!=0.f)?(unsigned short)0x3F80:(unsigned short)0;
                    zb.z = (znp[2]!=0.f)?(unsigned short)0x3F80:(unsigned short)0;
                    zb.w = (znp[3]!=0.f)?(unsigned short)0x3F80:(unsigned short)0;
                    h = f2bf(tnp[0]); hb.x = h; lb4.x = f2bf(tnp[0] - bf2f(h));
                    h = f2bf(tnp[1]); hb.y = h; lb4.y = f2bf(tnp[1] - bf2f(h));
                    h = f2bf(tnp[2]); hb.z = h; lb4.z = f2bf(tnp[2] - bf2f(h));
                    h = f2bf(tnp[3]); hb.w = h; lb4.w = f2bf(tnp[3] - bf2f(h));
                    *(ushort4*)&sm.v.aZ4[rj*576 + col] = zb;
                    *(ushort4*)&sm.v.aTH[rj*576 + col] = hb;
                    *(ushort4*)&sm.v.aTL[rj*576 + col] = lb4;
                }
                if (jj == 0) spk0 = anyspk; else spk1 = anyspk;
            }
            if (spk0 && j0 < 100) atomicOr(&sm.v.sjany[jp*2], 1);
            if (spk1 && j0+1 < 100) atomicOr(&sm.v.sjany[jp*2+1], 1);
            if (anyTq) atomicOr(&sm.v.sAnyTq, 1);
        }
        __syncthreads();
        if (tid < 16 && jb0 + tid < 100) g_t[b*100 + jb0 + tid] = sm.v.sjany[tid] ? 1.f : 0.f;
        if (tid == 0 && szv) szf[b*7 + jgg] = 0;
        // ---- STDP correlations for own 16 j rows (E(u) not needed at u==31) ----
        if (u < 31) {
            int m0i = 0;
            #pragma unroll
            for (int k = 0; k < 16; k++) m0i |= sm.v.sjany[k];
            bool m0 = (m0i != 0);
            bool mq = (sm.v.sAnyTq != 0);
            bool ea = m0 || mq;
            if (tid == 0) eaW[b*7 + jgg] = ea ? 1 : 0;
            if (!ea) return;
            for (int i2 = tid; i2 < 704; i2 += 448) sm.v.u.sB[10080 + i2] = 0;  // zero block
            int lane = tid & 63, wv = tid >> 6;
            int mode = wv >> 1, n = wv & 1;
            bool wact = (wv < 4);
            int p25 = n*16 + (lane & 15);
            int offB1, offB2;
            {
                int offH, offL, offZ;
                if (p25 < 25) {
                    int dy = p25/5, dx = p25 - dy*5;
                    offH = ((0*5 + dx)*672 + dy*24)*2;
                    offL = ((1*5 + dx)*672 + dy*24)*2;
                    offZ = ((2*5 + dx)*672 + dy*24)*2;
                } else { offH = offL = offZ = 10080*2; }
                offB1 = (mode == 0) ? offH : offZ;
                offB2 = (mode == 0) ? offL : offZ;
            }
            const unsigned short* A1 = (mode == 0) ? sm.v.aZ4 : sm.v.aTH;
            const unsigned short* A2 = (mode == 0) ? sm.v.aZ4 : sm.v.aTL;
            float* Ew = (mode == 0) ? EPw : EMw;
            int abase = (lane & 15)*576 + (lane >> 4)*8;
            const char* sBb = (const char*)sm.v.u.sB;
            #pragma unroll 1
            for (int c = 0; c < 30; ++c) {
                bool cAc = sm.v.sCA[c] != 0;
                __syncthreads();
                {   // stage B-planes for this c
                    const size_t pbase = (size_t)(b*30 + c)*784;
                    for (int idx = tid; idx < 784; idx += 448) {
                        int r = idx/28, col = idx - r*28;
                        #pragma unroll
                        for (int pl = 0; pl < 3; ++pl) {
                            bool need = (pl < 2) ? m0 : (cAc && mq);
                            if (!need) continue;
                            unsigned short vvv =
                                ((pl == 0) ? uhiR : (pl == 1) ? uloR : uz3R)[pbase + idx];
                            int base = pl*5*672 + r*24;
                            #pragma unroll
                            for (int dx = 0; dx < 5; ++dx) {
                                int xx = col - dx;
                                if (xx >= 0 && xx < 24) sm.v.u.sB[base + dx*672 + xx] = vvv;
                            }
                        }
                    }
                }
                __syncthreads();
                if (!wact) continue;
                f32x4 C = (f32x4){0.f, 0.f, 0.f, 0.f};
                bool go = (mode == 0) ? m0 : (mq && cAc);
                if (go) {
                    for (int ks = 0; ks < 18; ++ks) {
                        int kk = ks*32 + (lane >> 4)*8;
                        bfx8 a1 = *(const bfx8*)(A1 + abase + ks*32);
                        bfx8 a2 = *(const bfx8*)(A2 + abase + ks*32);
                        bfx8 b1v = *(const bfx8*)(sBb + offB1 + kk*2);
                        bfx8 b2v = *(const bfx8*)(sBb + offB2 + kk*2);
                        C = __builtin_amdgcn_mfma_f32_16x16x32_bf16(a1, b1v, C, 0, 0, 0);
                        C = __builtin_amdgcn_mfma_f32_16x16x32_bf16(a2, b2v, C, 0, 0, 0);
                    }
                }
                if (p25 < 25) {
                    #pragma unroll
                    for (int q = 0; q < 4; ++q) {
                        int j = jb0 + (lane >> 4)*4 + q;
                        if (j < 100)
                            Ew[(size_t)b*75000 + ((size_t)j*30 + c)*25 + p25] = C[q];
                    }
                }
            }
        }
        return;
    }

    // ===================== front, step t =====================
    if (t >= T) return;
    const int fb = blk - 224;
    const int og = fb & 7, by = fb >> 3;
    const int b = by >> 1, yh = by & 1, y0 = yh*28;

    const float* tp1r = ws + ((t&1) ? OTP1B : OTP1A);
    float*       tp1w = ws + ((t&1) ? OTP1A : OTP1B);
    const float* w1cur = ws + ((t&1) ? OW1B : OW1A);
    float*       w1nxt = ws + ((t&1) ? OW1A : OW1B);
    float*       partW = ws + ((t&1) ? OPARTB : OPARTA);
    const float* pprev = ws + ((t&1) ? OPARTA : OPARTB);
    int*         cnzW  = (int*)(ws + ((t&1) ? OCNZB : OCNZA));
    float*       z3W   = ws + ((t&1) ? OZ3B : OZ3A);
    unsigned short* uhiW = (unsigned short*)(ws + ((t&1) ? OPHIB : OPHIA));
    unsigned short* uloW = (unsigned short*)(ws + ((t&1) ? OPLOB : OPLOA));
    unsigned short* uz3W = (unsigned short*)(ws + ((t&1) ? OPZ3B : OPZ3A));
    float* vi0g = ws + OVI0; float* tq1g = ws + OTQ1;
    float* tp2g = ws + OTP2;
    int* qzf = (int*)(ws + OQZF);
    int* pzf = (int*)(ws + OPZF);

    const int prow = (b*2 + yh)*1500;   // this block's part row (slot-major)
    int qzOld = qzf[(b*8 + og)*2 + yh];
    {
        const float4* xs = (const float4*)(x + ((size_t)t*B + b)*4096) + y0*16;
        const float4* ts = (const float4*)(tp1r + (size_t)b*LD) + y0*15;
        for (int i2 = tid; i2 < 576; i2 += 448) ((float4*)sm.f.xsh)[i2] = xs[i2];
        for (int i2 = tid; i2 < 480; i2 += 448) ((float4*)sm.f.tsh)[i2] = ts[i2];
    }
    if (tid < 100) {
        int oo2 = tid / 25, pp = tid % 25;
        int o2 = og*4 + oo2; if (o2 > 29) o2 = 29;
        float2 wp = w1pair(w1cur, pprev, o2, pp, t);
        sm.f.wd[tid] = wp.x - wp.y;
    }
    if (fb < 4) {
        int e = fb*448 + tid;
        if (e < 1500) {
            int o = e/50, r = e%50, ch = r/25, pp = r%25;
            float2 wp = w1pair(w1cur, pprev, o, pp, t);
            w1nxt[e] = ch ? wp.y : wp.x;
        }
    }
    if (tid < 8) sm.f.sflags[tid] = 0;
    __syncthreads();
    float bias = b1[0] - b2[0];
    // DoG + tp1 trace (og==0 persists tp1)
    for (int idx = tid; idx < 1920; idx += 448) {
        int lr = idx / 60, c = idx % 60;
        float a = 0.f;
        #pragma unroll
        for (int kh = 0; kh < 5; kh++)
            #pragma unroll
            for (int kw = 0; kw < 5; kw++)
                a = fmaf(dk.v[kh*5+kw], sm.f.xsh[(lr+kh)*64 + c + kw], a);
        float zv = a + bias;
        sm.f.zsh[idx] = zv;
        float tp = sm.f.tsh[idx];
        tp = tp + DTTR*(zv - tp);
        sm.f.tsh[idx] = tp;
        if (og == 0) tp1w[(size_t)b*LD + (y0 + lr)*60 + c] = tp;
    }
    __syncthreads();
    int oo = tid & 3, xq = (tid >> 2) & 3, yv = tid >> 4;
    int o = og*4 + oo, xx0 = xq*14;
    bool valid = (o < 30);
    float zn[14], tn[14];
    float zs = 0.f, qs = 0.f;
    bool anym = false;
    if (valid) {
        float acc[14];
        #pragma unroll
        for (int k = 0; k < 14; k++) acc[k] = 0.f;
        #pragma unroll
        for (int kh = 0; kh < 5; kh++) {
            float rr[18];
            const float2* r2 = (const float2*)&sm.f.zsh[(yv+kh)*HD + xx0];
            #pragma unroll
            for (int i = 0; i < 9; i++) ((float2*)rr)[i] = r2[i];
            #pragma unroll
            for (int kw = 0; kw < 5; kw++) {
                float w = sm.f.wd[oo*25 + kh*5 + kw];
                #pragma unroll
                for (int k = 0; k < 14; k++) acc[k] = fmaf(w, rr[k+kw], acc[k]);
            }
        }
        // LIF0 (vi0 float4 = v.x,v.y,i.x,i.y) + tq1 (sticky-zero gated)
        float4* vi0p = (float4*)vi0g;
        float2* tq1p = (float2*)tq1g;
        size_t sb = ((size_t)((b*8 + og)*2 + yh)*7)*448 + tid;
        #pragma unroll
        for (int i = 0; i < 7; i++) {
            float4 vi = vi0p[sb + (size_t)i*448];
            float2 t2;
            if (qzOld) { t2.x = 0.f; t2.y = 0.f; }
            else t2 = tq1p[sb + (size_t)i*448];
            float4 vin;
            float2 tn2;
            bool sp = false;
            #pragma unroll
            for (int k = 0; k < 2; k++) {
                int e = i*2 + k;
                float vv = k ? vi.y : vi.x, cc = k ? vi.w : vi.z, tt = k ? t2.y : t2.x;
                float vd = vv + DTMEM*(cc - vv);
                float z = (vd > 15.0f) ? 1.0f : 0.0f;
                float vo = (1.0f - z)*vd;
                float io_ = (cc - DTSYN*cc) + acc[e];
                float tq = tt + DTTR*(z - tt);
                if (k) { vin.y = vo; vin.w = io_; tn2.y = tq; }
                else   { vin.x = vo; vin.z = io_; tn2.x = tq; }
                zn[e] = z; tn[e] = tq;
                sp = sp || (z != 0.f);
            }
            vi0p[sb + (size_t)i*448] = vin;
            if (!qzOld || sp) tq1p[sb + (size_t)i*448] = tn2;
        }
        #pragma unroll
        for (int k = 0; k < 14; k++) { zs += zn[k]; qs += tn[k]; }
        float mx[7];
        #pragma unroll
        for (int k = 0; k < 7; k++) mx[k] = fmaxf(zn[2*k], zn[2*k+1]);
        #pragma unroll
        for (int k = 0; k < 7; k++) {
            float pm = __shfl_xor(mx[k], 16, 64);   // y-partner (y^1)
            mx[k] = fmaxf(mx[k], pm);
        }
        if ((yv & 1) == 0) {
            int pzOld = pzf[b*30 + o];
            int py = yh*14 + (yv >> 1);
            size_t pb = ((size_t)(b*30 + o)*HP + py)*HP + xq*7;
            #pragma unroll
            for (int k = 0; k < 7; k++) {
                float m = mx[k];
                anym = anym || (m != 0.f);
                if (!pzOld || m != 0.f) {
                    z3W[pb + k] = m;
                    float tpv = pzOld ? 0.f : tp2g[pb + k];
                    float tnew = tpv + DTTR*(m - tpv);
                    tp2g[pb + k] = tnew;
                    unsigned short h = f2bf(tnew);
                    uhiW[pb + k] = h;
                    uloW[pb + k] = f2bf(tnew - bf2f(h));
                    uz3W[pb + k] = (m != 0.f) ? (unsigned short)0x3F80 : (unsigned short)0;
                }
            }
        }
    }
    if (anym) atomicOr(&sm.f.sflags[oo*2 + (xq >> 1)], 1);
    __syncthreads();
    int anyblk = sm.f.sflags[0]|sm.f.sflags[1]|sm.f.sflags[2]|sm.f.sflags[3]|
                 sm.f.sflags[4]|sm.f.sflags[5]|sm.f.sflags[6]|sm.f.sflags[7];
    if (tid < 8) {
        int o2 = og*4 + (tid >> 1);
        if (o2 < 30) cnzW[(b*30 + o2)*4 + yh*2 + (tid & 1)] = sm.f.sflags[tid];
    }
    if (tid < 4) {  // sticky plane-zero clear (benign cross-yh race: both write 0)
        int o2 = og*4 + tid;
        if (o2 < 30 && (sm.f.sflags[tid*2] | sm.f.sflags[tid*2+1])) pzf[b*30 + o2] = 0;
    }
    if (tid == 0 && qzOld && anyblk) qzf[(b*8 + og)*2 + yh] = 0;

    if (qzOld && !anyblk) {
        // tq1 was zero and no spikes fired: both correlation rows are exactly zero.
        if (tid < 100) {
            int oo2 = tid / 25, q = tid % 25;
            int o2 = og*4 + oo2;
            if (o2 < 30) {
                partW[prow + o2*50 + q] = 0.f;
                partW[prow + o2*50 + 25 + q] = 0.f;
            }
        }
        return;
    }
    int lane = tid & 63, wave = tid >> 6;
    // pass 1: minus correlation (unfold(z0) x tq1_new)
    {
        float a[25];
        #pragma unroll
        for (int pq = 0; pq < 25; pq++) a[pq] = 0.f;
        if (valid && qs != 0.f) {
            #pragma unroll
            for (int kh = 0; kh < 5; kh++) {
                float rr[18];
                const float2* r2 = (const float2*)&sm.f.zsh[(yv+kh)*HD + xx0];
                #pragma unroll
                for (int i = 0; i < 9; i++) ((float2*)rr)[i] = r2[i];
                #pragma unroll
                for (int kw = 0; kw < 5; kw++)
                    #pragma unroll
                    for (int k = 0; k < 14; k++)
                        a[kh*5+kw] = fmaf(rr[k+kw], tn[k], a[kh*5+kw]);
            }
        }
        #pragma unroll
        for (int q = 0; q < 25; q++) {
            float v = a[q];
            v += __shfl_xor(v, 4, 64);
            v += __shfl_xor(v, 8, 64);
            v += __shfl_xor(v, 16, 64);
            v += __shfl_xor(v, 32, 64);
            if (lane < 4) sm.f.red[wave*100 + lane*25 + q] = v;
        }
    }
    __syncthreads();
    if (tid < 100) {
        int oo2 = tid / 25, q = tid % 25;
        float s = 0.f;
        #pragma unroll
        for (int w = 0; w < 7; w++) s += sm.f.red[w*100 + oo2*25 + q];
        int o2 = og*4 + oo2;
        if (o2 < 30) partW[prow + o2*50 + 25 + q] = s;
    }
    __syncthreads();
    // pass 2: plus correlation (unfold(tp1_new) x z2)
    {
        float a[25];
        #pragma unroll
        for (int pq = 0; pq < 25; pq++) a[pq] = 0.f;
        if (valid && zs != 0.f) {
            #pragma unroll
            for (int kh = 0; kh < 5; kh++) {
                float rr[18];
                const float2* r2 = (const float2*)&sm.f.tsh[(yv+kh)*HD + xx0];
                #pragma unroll
                for (int i = 0; i < 9; i++) ((float2*)rr)[i] = r2[i];
                #pragma unroll
                for (int kw = 0; kw < 5; kw++)
                    #pragma unroll
                    for (int k = 0; k < 14; k++)
                        a[kh*5+kw] = fmaf(rr[k+kw], zn[k], a[kh*5+kw]);
            }
        }
        #pragma unroll
        for (int q = 0; q < 25; q++) {
            float v = a[q];
            v += __shfl_xor(v, 4, 64);
            v += __shfl_xor(v, 8, 64);
            v += __shfl_xor(v, 16, 64);
            v += __shfl_xor(v, 32, 64);
            if (lane < 4) sm.f.red[wave*100 + lane*25 + q] = v;
        }
    }
    __syncthreads();
    if (tid < 100) {
        int oo2 = tid / 25, q = tid % 25;
        float s = 0.f;
        #pragma unroll
        for (int w = 0; w < 7; w++) s += sm.f.red[w*100 + oo2*25 + q];
        int o2 = og*4 + oo2;
        if (o2 < 30) partW[prow + o2*50 + q] = s;
    }
}

// ================= k_prep: padded w2 + flag init =================
__global__ void k_prep(const float* __restrict__ w2, float* __restrict__ w2p,
                       int* __restrict__ qzf, int* __restrict__ pzf,
                       int* __restrict__ szf) {
    int e = blockIdx.x*blockDim.x + threadIdx.x;
    if (e < 75000) {
        int j = e / 750, r = e % 750, c = r / 25, p = r % 25;
        w2p[((size_t)j*30 + c)*28 + p] = w2[e];
    }
    if (e < 512) qzf[e] = 1;
    if (e < 960) pzf[e] = 1;
    if (e < 224) szf[e] = 1;
}

// ================= k_fc1b: batched fc1, grid (500 n, 4 t-quarters) =================
__global__ __launch_bounds__(256) void k_fc1b(
        const float* __restrict__ g_all, const float* __restrict__ fcw,
        const float* __restrict__ fcb, float* __restrict__ h_all) {
    __shared__ float red[8][4];
    int n = blockIdx.x, by = blockIdx.y, tid = threadIdx.x;
    const float4* w4 = (const float4*)(fcw + (size_t)n*3200);
    float4 wreg[4];
    #pragma unroll
    for (int i = 0; i < 4; i++) {
        int k = tid + 256*i;
        if (k < 800) wreg[i] = w4[k];
    }
    float accs[8];
    #pragma unroll
    for (int tt = 0; tt < 8; tt++) accs[tt] = 0.f;
    #pragma unroll 1
    for (int tt = 0; tt < 8; tt++) {
        int t = by*8 + tt;
        const float4* g4 = (const float4*)(g_all + (size_t)t*3200);
        float a = 0.f;
        #pragma unroll
        for (int i = 0; i < 4; i++) {
            int k = tid + 256*i;
            if (k < 800) {
                float4 gv = g4[k];
                a = fmaf(gv.x, wreg[i].x, a);
                a = fmaf(gv.y, wreg[i].y, a);
                a = fmaf(gv.z, wreg[i].z, a);
                a = fmaf(gv.w, wreg[i].w, a);
            }
        }
        accs[tt] = a;
    }
    int lane = tid & 63, wid = tid >> 6;
    #pragma unroll
    for (int tt = 0; tt < 8; tt++) {
        float v = accs[tt];
        #pragma unroll
        for (int s = 32; s >= 1; s >>= 1) v += __shfl_down(v, s, 64);
        if (lane == 0) red[tt][wid] = v;
    }
    __syncthreads();
    if (tid < 8)
        h_all[(size_t)(by*8 + tid)*500 + n] =
            red[tid][0] + red[tid][1] + red[tid][2] + red[tid][3] + fcb[n];
}

// ================= k_head_all: LIF2 + LI readout =================
__global__ __launch_bounds__(640) void k_head_all(
        const float* __restrict__ h_all, const float* __restrict__ outw,
        float* __restrict__ out) {
    __shared__ float spk[500];
    __shared__ float vout[10];
    int tid = threadIdx.x;
    int wid = tid >> 6, lane = tid & 63;
    float v2r = 0.f, i2r = 0.f;
    float vor = 0.f, ior = 0.f;
    #pragma unroll 1
    for (int t = 0; t < 32; t++) {
        if (tid < 500) {
            float cur = i2r;
            float vd = v2r + DTMEM*(cur - v2r);
            float z = (vd > 1.0f) ? 1.0f : 0.0f;
            v2r = (1.0f - z)*vd;
            i2r = (cur - DTSYN*cur) + h_all[t*500 + tid];
            spk[tid] = z;
        }
        __syncthreads();
        float acc = 0.f;
        for (int n = lane; n < 500; n += 64)
            acc = fmaf(spk[n], outw[wid*500 + n], acc);
        #pragma unroll
        for (int s = 32; s >= 1; s >>= 1) acc += __shfl_down(acc, s, 64);
        if (lane == 0) {
            float ij = ior + acc;
            float vn = vor + DTMEM*(ij - vor);
            ior = ij - DTSYN*ij;
            vor = vn;
            vout[wid] = vn;
        }
        __syncthreads();
        if (tid < 320) out[(size_t)t*320 + tid] = vout[tid % 10];
        __syncthreads();
    }
}

// ---------------- launcher ----------------
extern "C" void kernel_launch(void* const* d_in, const int* in_sizes, int n_in,
                              void* d_out, int out_size, void* d_ws, size_t ws_size,
                              hipStream_t stream) {
    const float* x    = (const float*)d_in[0];
    const float* b1   = (const float*)d_in[1];
    const float* b2   = (const float*)d_in[2];
    const float* w1   = (const float*)d_in[3];
    const float* w2   = (const float*)d_in[4];
    const float* fcw  = (const float*)d_in[5];
    const float* fcb  = (const float*)d_in[6];
    const float* outw = (const float*)d_in[7];
    float* ws  = (float*)d_ws;
    float* out = (float*)d_out;

    DK dk;
    {
        float g1[25], g2[25], s1 = 0.f, s2 = 0.f;
        for (int i = 0; i < 5; i++)
            for (int j = 0; j < 5; j++) {
                float ai = (float)(i - 2), aj = (float)(j - 2);
                float r2 = ai*ai + aj*aj;
                g1[i*5+j] = expf(-r2/2.0f);
                g2[i*5+j] = expf(-r2/8.0f);
                s1 += g1[i*5+j]; s2 += g2[i*5+j];
            }
        for (int k = 0; k < 25; k++) dk.v[k] = g1[k]/s1 - g2[k]/s2;
    }

    hipMemcpyAsync(ws + OW1A, w1, 1500*sizeof(float), hipMemcpyDeviceToDevice, stream);
    hipMemsetAsync(ws + OVI0, 0, (OZEROEND - OVI0)*sizeof(float), stream);
    k_prep<<<294, 256, 0, stream>>>(w2, ws + OW2A, (int*)(ws + OQZF),
                                    (int*)(ws + OPZF), (int*)(ws + OSZF));

    for (int t = 0; t <= T; ++t)
        k_step<<<736, 448, 0, stream>>>(x, b1, b2, ws, dk, t);

    k_fc1b<<<dim3(500, 4), 256, 0, stream>>>(ws + OG, fcw, fcb, ws + OHH);
    k_head_all<<<1, 640, 0, stream>>>(ws + OHH, outw, out);
}